// Round 1
// 8691.855 us; speedup vs baseline: 1.0414x; 1.0414x over previous
//
#include <hip/hip_runtime.h>
#include <math.h>

// ---------------------------------------------------------------------------
// PureTriXButterfly round 3: 2-phase double-buffered MFMA GEMM.
// Same numerics as round 2 (split-fp16 3-term MFMA, fp32 accum) but the
// grouped-GEMM K-loop is restructured from stage->drain->compute (every
// pipe ~20%) into the verified minimum-2-phase template: issue next tile's
// global_load_lds into buffer B, ds_read+MFMA on buffer A, then ONE
// hand-placed s_waitcnt vmcnt(0) + raw s_barrier AFTER the MFMA cluster.
// Loads overlap compute; the compiler's pre-barrier full drain is gone.
// setprio(1) wraps the MFMA cluster (load-issue vs MFMA role split).
// ---------------------------------------------------------------------------

constexpr int D    = 1024;
constexpr int T    = 16;
constexpr int KSEL = 4;
constexpr int PAD  = 128;   // slot padding per tile = GEMM M-tile

typedef _Float16 f16;
typedef f16 f16x8 __attribute__((ext_vector_type(8)));
typedef f16 f16x4 __attribute__((ext_vector_type(4)));
typedef float f32x4 __attribute__((ext_vector_type(4)));
typedef unsigned int u32;

__device__ __forceinline__ float gelu_f(float v) {
    return 0.5f * v * (1.0f + erff(v * 0.70710678118654752440f));
}

__device__ __forceinline__ void async16(const void* g, void* l) {
    __builtin_amdgcn_global_load_lds(
        (const __attribute__((address_space(1))) u32*)g,
        (__attribute__((address_space(3))) u32*)l, 16, 0, 0);
}

// ---------------- input encode: fourier -> @Win -> LN -> GELU (+split) -----
__global__ __launch_bounds__(256) void encode_kernel(
    const int* __restrict__ A, const int* __restrict__ Bv,
    const float* __restrict__ Win, const float* __restrict__ bin_,
    const float* __restrict__ g_in, const float* __restrict__ b_ln,
    float* __restrict__ x, f16* __restrict__ xhi, f16* __restrict__ xlo)
{
    const int row = blockIdx.x, tid = threadIdx.x;
    const float c = (float)(6.283185307179586476925286766559 / 16.0);
    float feat[32];
    const float xa = (float)A[row] * c;
    const float xb = (float)Bv[row] * c;
#pragma unroll
    for (int k = 0; k < 8; ++k) {
        const float f = (float)(1 << k);
        float aa = xa * f, ab = xb * f;
        feat[k]      = sinf(aa);
        feat[8 + k]  = cosf(aa);
        feat[16 + k] = sinf(ab);
        feat[24 + k] = cosf(ab);
    }
    const int d = tid << 2;
    float4 acc = *(const float4*)(bin_ + d);
#pragma unroll
    for (int f = 0; f < 32; ++f) {
        const float4 w = *(const float4*)(Win + (size_t)f * D + d);
        const float ff = feat[f];
        acc.x += ff * w.x; acc.y += ff * w.y; acc.z += ff * w.z; acc.w += ff * w.w;
    }
    __shared__ float red[256];
    red[tid] = acc.x + acc.y + acc.z + acc.w;
    __syncthreads();
    for (int st = 128; st > 0; st >>= 1) { if (tid < st) red[tid] += red[tid + st]; __syncthreads(); }
    const float mean = red[0] * (1.0f / 1024.0f);
    __syncthreads();
    float dx0 = acc.x - mean, dx1 = acc.y - mean, dx2 = acc.z - mean, dx3 = acc.w - mean;
    red[tid] = dx0 * dx0 + dx1 * dx1 + dx2 * dx2 + dx3 * dx3;
    __syncthreads();
    for (int st = 128; st > 0; st >>= 1) { if (tid < st) red[tid] += red[tid + st]; __syncthreads(); }
    const float rstd = rsqrtf(red[0] * (1.0f / 1024.0f) + 1e-5f);
    const float4 g4 = *(const float4*)(g_in + d);
    const float4 b4 = *(const float4*)(b_ln + d);
    float4 o;
    o.x = gelu_f(dx0 * rstd * g4.x + b4.x);
    o.y = gelu_f(dx1 * rstd * g4.y + b4.y);
    o.z = gelu_f(dx2 * rstd * g4.z + b4.z);
    o.w = gelu_f(dx3 * rstd * g4.w + b4.w);
    *(float4*)(x + (size_t)row * D + d) = o;
    f16x4 hv, lv;
    hv[0] = (f16)o.x; lv[0] = (f16)(o.x - (float)hv[0]);
    hv[1] = (f16)o.y; lv[1] = (f16)(o.y - (float)hv[1]);
    hv[2] = (f16)o.z; lv[2] = (f16)(o.z - (float)hv[2]);
    hv[3] = (f16)o.w; lv[3] = (f16)(o.w - (float)hv[3]);
    *(f16x4*)(xhi + (size_t)row * D + d) = hv;
    *(f16x4*)(xlo + (size_t)row * D + d) = lv;
}

// ---------------- per-layer init ------------------------------------------
__global__ __launch_bounds__(256) void init_layer_kernel(
    float* __restrict__ outacc, int* __restrict__ rowlist, int* __restrict__ counts,
    long n, int maxslots)
{
    const long i = (long)blockIdx.x * blockDim.x + threadIdx.x;
    if (i < n) outacc[i] = 0.0f;
    if (i < maxslots) rowlist[i] = -1;
    if (i < T) counts[i] = 0;
}

// ---------------- router: logits, softmax, top-4 ---------------------------
__global__ __launch_bounds__(64) void router_kernel(
    const float* __restrict__ x, const float* __restrict__ Wr, int layer,
    float* __restrict__ gates, int* __restrict__ topi, int* __restrict__ counts)
{
    const int row = blockIdx.x, lane = threadIdx.x;
    __shared__ float xs[D];
    __shared__ float ls[T];
    for (int j = lane; j < D / 4; j += 64)
        *(float4*)&xs[j * 4] = *(const float4*)(x + (size_t)row * D + j * 4);
    __syncthreads();
    const int t = lane & 15, seg = lane >> 4;
    const float* wr = Wr + (size_t)layer * D * T;
    float acc = 0.0f;
    const int d0 = seg * 256;
    for (int j = 0; j < 256; ++j) {
        const int d = d0 + j;
        acc += xs[d] * wr[d * T + t];
    }
    acc += __shfl_down(acc, 32);
    acc += __shfl_down(acc, 16);
    if (lane < 16) ls[lane] = acc;
    __syncthreads();
    if (lane == 0) {
        float m = ls[0];
        for (int i = 1; i < 16; ++i) m = fmaxf(m, ls[i]);
        float p[16], ssum = 0.0f;
        for (int i = 0; i < 16; ++i) { p[i] = expf(ls[i] - m); ssum += p[i]; }
        const float inv = 1.0f / ssum;
        bool sel[16];
        for (int i = 0; i < 16; ++i) sel[i] = false;
        for (int j = 0; j < KSEL; ++j) {
            int best = 0; float bvv = -1e30f;
            for (int i = 0; i < 16; ++i)
                if (!sel[i] && ls[i] > bvv) { bvv = ls[i]; best = i; }
            sel[best] = true;
            topi[row * KSEL + j]  = best;
            gates[row * KSEL + j] = p[best] * inv;
            atomicAdd(&counts[best], 1);
        }
    }
}

// ---------------- scan: padded per-tile offsets ----------------------------
__global__ void scan_kernel(const int* __restrict__ counts, int* __restrict__ offp,
                            int* __restrict__ cur)
{
    if (threadIdx.x == 0) {
        int off = 0;
        for (int t = 0; t < T; ++t) {
            offp[t] = off;
            cur[t] = 0;
            off += ((counts[t] + PAD - 1) / PAD) * PAD;
        }
        offp[T] = off;
    }
}

// ---------------- scatter rows into tile slot lists ------------------------
__global__ __launch_bounds__(256) void scatter_kernel(
    const int* __restrict__ topi, const float* __restrict__ gates,
    const int* __restrict__ offp, int* __restrict__ cur,
    int* __restrict__ rowlist, float* __restrict__ slotgate, int Bn)
{
    const int row = blockIdx.x * blockDim.x + threadIdx.x;
    if (row >= Bn) return;
    for (int j = 0; j < KSEL; ++j) {
        const int t = topi[row * KSEL + j];
        const int pos = atomicAdd(&cur[t], 1);
        const int s = offp[t] + pos;
        rowlist[s] = row;
        slotgate[s] = gates[row * KSEL + j];
    }
}

// ---------------- transpose + hi/lo split: W(K,N) fp32 -> Wt(N,K) f16 ------
__global__ __launch_bounds__(256) void tspl_kernel(
    const float* __restrict__ W, f16* __restrict__ ohi, f16* __restrict__ olo,
    int K, int N)
{
    const size_t zoff = (size_t)blockIdx.z * K * N;
    const float* Wz = W + zoff;
    const int r0 = blockIdx.x * 32, c0 = blockIdx.y * 32;
    __shared__ float tile[32][33];
    const int tr = threadIdx.x >> 3, tc = (threadIdx.x & 7) * 4;
    const float4 v = *(const float4*)(Wz + (size_t)(r0 + tr) * N + c0 + tc);
    tile[tr][tc + 0] = v.x; tile[tr][tc + 1] = v.y;
    tile[tr][tc + 2] = v.z; tile[tr][tc + 3] = v.w;
    __syncthreads();
    f16x4 h4, l4;
#pragma unroll
    for (int q = 0; q < 4; ++q) {
        const float f = tile[tc + q][tr];
        const f16 h = (f16)f;
        h4[q] = h; l4[q] = (f16)(f - (float)h);
    }
    const size_t oidx = zoff + (size_t)(c0 + tr) * K + r0 + tc;
    *(f16x4*)(ohi + oidx) = h4;
    *(f16x4*)(olo + oidx) = l4;
}

// ---------------- split-fp16 MFMA grouped GEMM (2-phase pipelined) ---------
// C(128x128) = A(128x1024) @ B(1024x128), 3-term hi/lo split, fp32 accum.
// mode 0: FFN GEMM1  - A gathered from x planes via rowlist; gelu; H hi/lo out
// mode 1: FFN GEMM2  - A = H planes (chunk-local); gate * y atomicAdd outF
// mode 2: head GEMM  - A = x planes (row = slot); gelu; fp32 out (ld Ncols)
__global__ __launch_bounds__(256) void mfma_gemm_kernel(
    const f16* __restrict__ Ahi, const f16* __restrict__ Alo,
    const int* __restrict__ rowlist, const int* __restrict__ offp,
    const f16* __restrict__ Whi, const f16* __restrict__ Wlo,
    const float* __restrict__ biasbase, const float* __restrict__ slotgate,
    f16* __restrict__ Hhi, f16* __restrict__ Hlo,
    float* __restrict__ outF,
    int mode, int s0, int Ncols, int plainM)
{
    const int slot0 = s0 + blockIdx.x * 128;
    int t = 0;
    if (mode != 2) {
        if (slot0 >= offp[T]) return;
        while (offp[t + 1] <= slot0) ++t;
    } else {
        if (slot0 >= plainM) return;
    }
    const int tid = threadIdx.x;
    const int wave = tid >> 6, lane = tid & 63;
    const int n0 = blockIdx.y * 128;

    // LDS: 2 buffers x [plane 0=Ahi 1=Alo 2=Bhi 3=Blo][k-quad][row/col][8] = 64 KB
    __shared__ f16 lds[2][4][4][128][8];

    // 32 wave-issues per K-step; wave w takes iss = w + 4*s (wave-uniform
    // buffer/base per issue; per-lane global addresses may scatter).
    const f16* gp[8];
    f16* lp[8];           // destination inside buffer 0; +16384 elems = buffer 1
#pragma unroll
    for (int s = 0; s < 8; ++s) {
        const int iss = wave + 4 * s;
        const int b = iss >> 3, sub = iss & 7;
        const int c = sub * 64 + lane;
        const int q = c >> 7, idx = c & 127;
        lp[s] = &lds[0][0][0][0][0] + ((size_t)b * 4096 + (size_t)c * 8);
        if (b < 2) {
            const f16* plane = b ? Alo : Ahi;
            int row;
            if (mode == 0) { const int r = rowlist[slot0 + idx]; row = r < 0 ? 0 : r; }
            else if (mode == 1) row = slot0 - s0 + idx;
            else row = slot0 + idx;
            gp[s] = plane + (size_t)row * 1024 + q * 8;
        } else {
            const f16* plane = (b == 3) ? Wlo : Whi;
            gp[s] = plane + ((size_t)t * Ncols + n0 + idx) * 1024 + q * 8;
        }
    }

    f32x4 acc[4][4];
#pragma unroll
    for (int i = 0; i < 4; ++i)
#pragma unroll
        for (int j = 0; j < 4; ++j) acc[i][j] = (f32x4){0.f, 0.f, 0.f, 0.f};

    const int wr = wave >> 1, wc = wave & 1;
    const int qd = lane >> 4, m16 = lane & 15;

    // ---- prologue: stage K-step 0 into buffer 0, drain, sync ----
#pragma unroll
    for (int s = 0; s < 8; ++s) { async16(gp[s], lp[s]); gp[s] += 32; }
    asm volatile("s_waitcnt vmcnt(0)" ::: "memory");
    __builtin_amdgcn_s_barrier();
    asm volatile("" ::: "memory");

    // ---- main loop: 31 pipelined steps (stage t+1 || compute t) ----
#pragma unroll 2
    for (int kt = 0; kt < 31; ++kt) {
        const int cur = kt & 1, nxt = cur ^ 1;
        // issue next K-step's loads into the other buffer (in flight during MFMA)
#pragma unroll
        for (int s = 0; s < 8; ++s) { async16(gp[s], lp[s] + nxt * 16384); gp[s] += 32; }

        f16x8 ah[4], al[4], bh[4], bl[4];
#pragma unroll
        for (int i = 0; i < 4; ++i) {
            ah[i] = *(const f16x8*)&lds[cur][0][qd][wr * 64 + i * 16 + m16][0];
            al[i] = *(const f16x8*)&lds[cur][1][qd][wr * 64 + i * 16 + m16][0];
            bh[i] = *(const f16x8*)&lds[cur][2][qd][wc * 64 + i * 16 + m16][0];
            bl[i] = *(const f16x8*)&lds[cur][3][qd][wc * 64 + i * 16 + m16][0];
        }
        __builtin_amdgcn_s_setprio(1);
#pragma unroll
        for (int i = 0; i < 4; ++i)
#pragma unroll
            for (int j = 0; j < 4; ++j) {
                acc[i][j] = __builtin_amdgcn_mfma_f32_16x16x32_f16(ah[i], bh[j], acc[i][j], 0, 0, 0);
                acc[i][j] = __builtin_amdgcn_mfma_f32_16x16x32_f16(al[i], bh[j], acc[i][j], 0, 0, 0);
                acc[i][j] = __builtin_amdgcn_mfma_f32_16x16x32_f16(ah[i], bl[j], acc[i][j], 0, 0, 0);
            }
        __builtin_amdgcn_s_setprio(0);
        // single drain AFTER compute: next tile's loads had the whole MFMA
        // cluster to land; then sync so no wave reads/overwrites early.
        asm volatile("s_waitcnt vmcnt(0)" ::: "memory");
        __builtin_amdgcn_s_barrier();
        asm volatile("" ::: "memory");
    }

    // ---- epilogue compute: K-step 31 lives in buffer 1 ----
    {
        f16x8 ah[4], al[4], bh[4], bl[4];
#pragma unroll
        for (int i = 0; i < 4; ++i) {
            ah[i] = *(const f16x8*)&lds[1][0][qd][wr * 64 + i * 16 + m16][0];
            al[i] = *(const f16x8*)&lds[1][1][qd][wr * 64 + i * 16 + m16][0];
            bh[i] = *(const f16x8*)&lds[1][2][qd][wc * 64 + i * 16 + m16][0];
            bl[i] = *(const f16x8*)&lds[1][3][qd][wc * 64 + i * 16 + m16][0];
        }
        __builtin_amdgcn_s_setprio(1);
#pragma unroll
        for (int i = 0; i < 4; ++i)
#pragma unroll
            for (int j = 0; j < 4; ++j) {
                acc[i][j] = __builtin_amdgcn_mfma_f32_16x16x32_f16(ah[i], bh[j], acc[i][j], 0, 0, 0);
                acc[i][j] = __builtin_amdgcn_mfma_f32_16x16x32_f16(al[i], bh[j], acc[i][j], 0, 0, 0);
                acc[i][j] = __builtin_amdgcn_mfma_f32_16x16x32_f16(ah[i], bl[j], acc[i][j], 0, 0, 0);
            }
        __builtin_amdgcn_s_setprio(0);
    }

    float bj[4];
#pragma unroll
    for (int j = 0; j < 4; ++j)
        bj[j] = biasbase[(size_t)t * Ncols + n0 + wc * 64 + j * 16 + m16];

    if (mode == 0) {
#pragma unroll
        for (int i = 0; i < 4; ++i)
#pragma unroll
            for (int r = 0; r < 4; ++r) {
                const int ls_ = slot0 - s0 + wr * 64 + i * 16 + qd * 4 + r;
                f16* ph = Hhi + (size_t)ls_ * 1024 + n0 + wc * 64 + m16;
                f16* pl = Hlo + (size_t)ls_ * 1024 + n0 + wc * 64 + m16;
#pragma unroll
                for (int j = 0; j < 4; ++j) {
                    const float v = gelu_f(acc[i][j][r] + bj[j]);
                    const f16 h = (f16)v;
                    ph[j * 16] = h;
                    pl[j * 16] = (f16)(v - (float)h);
                }
            }
    } else if (mode == 1) {
#pragma unroll
        for (int i = 0; i < 4; ++i)
#pragma unroll
            for (int r = 0; r < 4; ++r) {
                const int s_ = slot0 + wr * 64 + i * 16 + qd * 4 + r;
                const int grow = rowlist[s_];
                if (grow < 0) continue;
                const float g = slotgate[s_];
                float* op = outF + (size_t)grow * 1024 + n0 + wc * 64 + m16;
#pragma unroll
                for (int j = 0; j < 4; ++j)
                    atomicAdd(op + j * 16, g * (acc[i][j][r] + bj[j]));
            }
    } else {
#pragma unroll
        for (int i = 0; i < 4; ++i)
#pragma unroll
            for (int r = 0; r < 4; ++r) {
                const int row = slot0 + wr * 64 + i * 16 + qd * 4 + r;
                float* op = outF + (size_t)row * Ncols + n0 + wc * 64 + m16;
#pragma unroll
                for (int j = 0; j < 4; ++j)
                    op[j * 16] = gelu_f(acc[i][j][r] + bj[j]);
            }
    }
}

// ---------------- residual + LN (+split x) ---------------------------------
__global__ __launch_bounds__(256) void ln_kernel(
    float* __restrict__ x, const float* __restrict__ res,
    const float* __restrict__ g, const float* __restrict__ b,
    f16* __restrict__ xhi, f16* __restrict__ xlo)
{
    const int row = blockIdx.x, tid = threadIdx.x;
    const int d = tid << 2;
    float4 v = *(float4*)(x + (size_t)row * D + d);
    const float4 r = *(const float4*)(res + (size_t)row * D + d);
    v.x += r.x; v.y += r.y; v.z += r.z; v.w += r.w;
    __shared__ float red[256];
    red[tid] = v.x + v.y + v.z + v.w;
    __syncthreads();
    for (int st = 128; st > 0; st >>= 1) { if (tid < st) red[tid] += red[tid + st]; __syncthreads(); }
    const float mean = red[0] * (1.0f / 1024.0f);
    __syncthreads();
    const float dx0 = v.x - mean, dx1 = v.y - mean, dx2 = v.z - mean, dx3 = v.w - mean;
    red[tid] = dx0 * dx0 + dx1 * dx1 + dx2 * dx2 + dx3 * dx3;
    __syncthreads();
    for (int st = 128; st > 0; st >>= 1) { if (tid < st) red[tid] += red[tid + st]; __syncthreads(); }
    const float rstd = rsqrtf(red[0] * (1.0f / 1024.0f) + 1e-5f);
    const float4 g4 = *(const float4*)(g + d);
    const float4 b4 = *(const float4*)(b + d);
    float4 o;
    o.x = dx0 * rstd * g4.x + b4.x;
    o.y = dx1 * rstd * g4.y + b4.y;
    o.z = dx2 * rstd * g4.z + b4.z;
    o.w = dx3 * rstd * g4.w + b4.w;
    *(float4*)(x + (size_t)row * D + d) = o;
    f16x4 hv, lv;
    hv[0] = (f16)o.x; lv[0] = (f16)(o.x - (float)hv[0]);
    hv[1] = (f16)o.y; lv[1] = (f16)(o.y - (float)hv[1]);
    hv[2] = (f16)o.z; lv[2] = (f16)(o.z - (float)hv[2]);
    hv[3] = (f16)o.w; lv[3] = (f16)(o.w - (float)hv[3]);
    *(f16x4*)(xhi + (size_t)row * D + d) = hv;
    *(f16x4*)(xlo + (size_t)row * D + d) = lv;
}

// ---------------- final small head ----------------------------------------
__global__ __launch_bounds__(64) void head_final_kernel(
    const float* __restrict__ Hs, const float* __restrict__ Hd,
    const float* __restrict__ Ws2, const float* __restrict__ bs2,
    const float* __restrict__ Wd2, const float* __restrict__ bd2,
    float* __restrict__ outp)
{
    const int row = blockIdx.x, lane = threadIdx.x;
    float acc[11] = {};
    for (int m = 0; m < 8; ++m) {
        const int k = lane + 64 * m;
        const float hs = Hs[(size_t)row * 512 + k];
#pragma unroll
        for (int j = 0; j < 5; ++j) acc[j] += hs * Ws2[k * 5 + j];
        const float hd = Hd[(size_t)row * 512 + k];
#pragma unroll
        for (int j = 0; j < 6; ++j) acc[5 + j] += hd * Wd2[k * 6 + j];
    }
#pragma unroll
    for (int off = 32; off > 0; off >>= 1)
#pragma unroll
        for (int j = 0; j < 11; ++j) acc[j] += __shfl_down(acc[j], off);
    if (lane == 0) {
        for (int j = 0; j < 5; ++j) outp[(size_t)row * 11 + j] = acc[j] + bs2[j];
        for (int j = 0; j < 6; ++j) outp[(size_t)row * 11 + 5 + j] = acc[5 + j] + bd2[j];
    }
}

// ---------------------------------------------------------------------------
extern "C" void kernel_launch(void* const* d_in, const int* in_sizes, int n_in,
                              void* d_out, int out_size, void* d_ws, size_t ws_size,
                              hipStream_t stream)
{
    const int*   a    = (const int*)d_in[0];
    const int*   bI   = (const int*)d_in[1];
    const float* Win  = (const float*)d_in[2];
    const float* bin_ = (const float*)d_in[3];
    const float* g_in = (const float*)d_in[4];
    const float* b_ln = (const float*)d_in[5];
    const float* Wr   = (const float*)d_in[6];
    const float* W1   = (const float*)d_in[7];
    const float* b1   = (const float*)d_in[8];
    const float* W2   = (const float*)d_in[9];
    const float* b2   = (const float*)d_in[10];
    const float* g_l  = (const float*)d_in[11];
    const float* b_l  = (const float*)d_in[12];
    const float* Ws1  = (const float*)d_in[13];
    const float* bs1  = (const float*)d_in[14];
    const float* Ws2  = (const float*)d_in[15];
    const float* bs2  = (const float*)d_in[16];
    const float* Wd1  = (const float*)d_in[17];
    const float* bd1  = (const float*)d_in[18];
    const float* Wd2  = (const float*)d_in[19];
    const float* bd2  = (const float*)d_in[20];
    const int Bn = in_sizes[0];                 // 16384
    float* outF = (float*)d_out;

    const long maxslots = (long)Bn * KSEL + (long)T * PAD;  // 67584

    // ---- workspace carve (256 B aligned) ----
    char* p = (char*)d_ws;
    auto alloc = [&](size_t bytes) -> char* {
        char* r = p;
        p += (bytes + 255) & ~(size_t)255;
        return r;
    };
    float* x      = (float*)alloc((size_t)Bn * D * 4);
    f16*   xhi    = (f16*)alloc((size_t)Bn * D * 2);
    f16*   xlo    = (f16*)alloc((size_t)Bn * D * 2);
    float* outacc = (float*)alloc((size_t)Bn * D * 4);
    f16* WtAh = (f16*)alloc((size_t)T * D * D * 2);
    f16* WtAl = (f16*)alloc((size_t)T * D * D * 2);
    f16* WtBh = (f16*)alloc((size_t)T * D * D * 2);
    f16* WtBl = (f16*)alloc((size_t)T * D * D * 2);
    f16* Wtsh = (f16*)alloc((size_t)D * 512 * 2);
    f16* Wtsl = (f16*)alloc((size_t)D * 512 * 2);
    f16* Wtdh = (f16*)alloc((size_t)D * 512 * 2);
    f16* Wtdl = (f16*)alloc((size_t)D * 512 * 2);
    float* gates    = (float*)alloc((size_t)Bn * KSEL * 4);
    float* slotgate = (float*)alloc((size_t)maxslots * 4);
    int*   topi     = (int*)alloc((size_t)Bn * KSEL * 4);
    int*   rowlist  = (int*)alloc((size_t)maxslots * 4);
    int*   counts   = (int*)alloc(T * 4);
    int*   offp     = (int*)alloc((T + 1) * 4);
    int*   cur      = (int*)alloc(T * 4);
    const size_t used = (size_t)(p - (char*)d_ws);
    const size_t avail = (ws_size > used) ? (ws_size - used) : 0;

    // H chunk: Hhi+Hlo = 4096 B per slot. Heads later overlay fp32 Hs/Hd here.
    long hcap = (long)(avail / 4096);
    hcap &= ~(long)(PAD - 1);
    if (hcap > maxslots) hcap = maxslots;
    if (hcap < Bn) hcap = Bn;    // floor so head buffers (Bn*512*2 fp32) fit
    f16* Hhi = (f16*)p;
    f16* Hlo = Hhi + (size_t)hcap * D;
    float* Hs = (float*)p;
    float* Hd = Hs + (size_t)Bn * 512;
    const int nchunks = (int)((maxslots + hcap - 1) / hcap);
    const int mblocks = (int)(hcap / PAD);

    // ---- launches ----
    encode_kernel<<<Bn, 256, 0, stream>>>(a, bI, Win, bin_, g_in, b_ln, x, xhi, xlo);
    tspl_kernel<<<dim3(32, 16, 1), 256, 0, stream>>>(Ws1, Wtsh, Wtsl, D, 512);
    tspl_kernel<<<dim3(32, 16, 1), 256, 0, stream>>>(Wd1, Wtdh, Wtdl, D, 512);

    const long initn = (long)Bn * D;
    const int initblocks = (int)((initn + 255) / 256);
    for (int i = 0; i < 3; ++i) {
        init_layer_kernel<<<initblocks, 256, 0, stream>>>(outacc, rowlist, counts,
                                                          initn, (int)maxslots);
        router_kernel<<<Bn, 64, 0, stream>>>(x, Wr, i, gates, topi, counts);
        scan_kernel<<<1, 64, 0, stream>>>(counts, offp, cur);
        scatter_kernel<<<(Bn + 255) / 256, 256, 0, stream>>>(topi, gates, offp, cur,
                                                             rowlist, slotgate, Bn);
        tspl_kernel<<<dim3(32, 32, 16), 256, 0, stream>>>(W1 + (size_t)i * T * D * D,
                                                          WtAh, WtAl, D, D);
        tspl_kernel<<<dim3(32, 32, 16), 256, 0, stream>>>(W2 + (size_t)i * T * D * D,
                                                          WtBh, WtBl, D, D);
        const float* b1i = b1 + (size_t)i * T * D;
        const float* b2i = b2 + (size_t)i * T * D;
        for (int c = 0; c < nchunks; ++c) {
            const int s0 = (int)((long)c * hcap);
            dim3 grid(mblocks, D / 128);
            mfma_gemm_kernel<<<grid, 256, 0, stream>>>(
                xhi, xlo, rowlist, offp, WtAh, WtAl, b1i, nullptr,
                Hhi, Hlo, nullptr, 0, s0, D, 0);
            mfma_gemm_kernel<<<grid, 256, 0, stream>>>(
                Hhi, Hlo, rowlist, offp, WtBh, WtBl, b2i, slotgate,
                nullptr, nullptr, outacc, 1, s0, D, 0);
        }
        ln_kernel<<<Bn, 256, 0, stream>>>(x, outacc, g_l + (size_t)i * D,
                                          b_l + (size_t)i * D, xhi, xlo);
    }

    // heads: Hs = gelu(x@Ws1+bs1), Hd = gelu(x@Wd1+bd1) via MFMA, then tiny head
    dim3 gh(Bn / 128, 512 / 128);
    mfma_gemm_kernel<<<gh, 256, 0, stream>>>(
        xhi, xlo, nullptr, nullptr, Wtsh, Wtsl, bs1, nullptr,
        nullptr, nullptr, Hs, 2, 0, 512, Bn);
    mfma_gemm_kernel<<<gh, 256, 0, stream>>>(
        xhi, xlo, nullptr, nullptr, Wtdh, Wtdl, bd1, nullptr,
        nullptr, nullptr, Hd, 2, 0, 512, Bn);
    head_final_kernel<<<Bn, 64, 0, stream>>>(Hs, Hd, Ws2, bs2, Wd2, bd2, outF);
}

// Round 4
// 7711.064 us; speedup vs baseline: 1.1738x; 1.1272x over previous
//
#include <hip/hip_runtime.h>
#include <math.h>

// ---------------------------------------------------------------------------
// PureTriXButterfly round 6: K-blocked coalesced staging, WITHOUT the XCD
// remap (bisect: rounds 4/5 died to container failures twice; this keeps the
// core request-count fix and reverts the grid handling to round-3's proven
// 2-D form). Defensive clamps added on the tile-search loop and gathered rows.
//
// Core theory (from round-3 counters: all pipes ~20%, ~7800 cyc/K-step vs
// ~500 of work): staging was memory-REQUEST-bound — every global_load_lds
// scattered 64 lanes to 64 distinct cache lines (16B slivers of 2KB-strided
// rows). Fix: all GEMM operands stored K-step-blocked [ks][row][32 halves]
// so each staging instruction reads a contiguous 1KB run (16 lines/instr).
// A chunk-XOR (c ^= (row>>1)&3) on the staging SOURCE address (LDS linear,
// G21) and the same XOR on frag reads keeps ds_read_b128 bank-conflict-free
// at the 64B row stride. Numerics bit-identical to rounds 2-5.
// ---------------------------------------------------------------------------

constexpr int D    = 1024;
constexpr int T    = 16;
constexpr int KSEL = 4;
constexpr int PAD  = 128;   // slot padding per tile = GEMM M-tile

typedef _Float16 f16;
typedef f16 f16x8 __attribute__((ext_vector_type(8)));
typedef f16 f16x4 __attribute__((ext_vector_type(4)));
typedef float f32x4 __attribute__((ext_vector_type(4)));
typedef unsigned int u32;

__device__ __forceinline__ float gelu_f(float v) {
    return 0.5f * v * (1.0f + erff(v * 0.70710678118654752440f));
}

__device__ __forceinline__ void async16(const void* g, void* l) {
    __builtin_amdgcn_global_load_lds(
        (const __attribute__((address_space(1))) u32*)g,
        (__attribute__((address_space(3))) u32*)l, 16, 0, 0);
}

// ---------------- input encode: fourier -> @Win -> LN -> GELU (+split) -----
// xhi/xlo are stored K-blocked: element (row, k) at [k>>5][row][k&31].
__global__ __launch_bounds__(256) void encode_kernel(
    const int* __restrict__ A, const int* __restrict__ Bv,
    const float* __restrict__ Win, const float* __restrict__ bin_,
    const float* __restrict__ g_in, const float* __restrict__ b_ln,
    float* __restrict__ x, f16* __restrict__ xhi, f16* __restrict__ xlo, int Bn)
{
    const int row = blockIdx.x, tid = threadIdx.x;
    const float c = (float)(6.283185307179586476925286766559 / 16.0);
    float feat[32];
    const float xa = (float)A[row] * c;
    const float xb = (float)Bv[row] * c;
#pragma unroll
    for (int k = 0; k < 8; ++k) {
        const float f = (float)(1 << k);
        float aa = xa * f, ab = xb * f;
        feat[k]      = sinf(aa);
        feat[8 + k]  = cosf(aa);
        feat[16 + k] = sinf(ab);
        feat[24 + k] = cosf(ab);
    }
    const int d = tid << 2;
    float4 acc = *(const float4*)(bin_ + d);
#pragma unroll
    for (int f = 0; f < 32; ++f) {
        const float4 w = *(const float4*)(Win + (size_t)f * D + d);
        const float ff = feat[f];
        acc.x += ff * w.x; acc.y += ff * w.y; acc.z += ff * w.z; acc.w += ff * w.w;
    }
    __shared__ float red[256];
    red[tid] = acc.x + acc.y + acc.z + acc.w;
    __syncthreads();
    for (int st = 128; st > 0; st >>= 1) { if (tid < st) red[tid] += red[tid + st]; __syncthreads(); }
    const float mean = red[0] * (1.0f / 1024.0f);
    __syncthreads();
    float dx0 = acc.x - mean, dx1 = acc.y - mean, dx2 = acc.z - mean, dx3 = acc.w - mean;
    red[tid] = dx0 * dx0 + dx1 * dx1 + dx2 * dx2 + dx3 * dx3;
    __syncthreads();
    for (int st = 128; st > 0; st >>= 1) { if (tid < st) red[tid] += red[tid + st]; __syncthreads(); }
    const float rstd = rsqrtf(red[0] * (1.0f / 1024.0f) + 1e-5f);
    const float4 g4 = *(const float4*)(g_in + d);
    const float4 b4 = *(const float4*)(b_ln + d);
    float4 o;
    o.x = gelu_f(dx0 * rstd * g4.x + b4.x);
    o.y = gelu_f(dx1 * rstd * g4.y + b4.y);
    o.z = gelu_f(dx2 * rstd * g4.z + b4.z);
    o.w = gelu_f(dx3 * rstd * g4.w + b4.w);
    *(float4*)(x + (size_t)row * D + d) = o;
    f16x4 hv, lv;
    hv[0] = (f16)o.x; lv[0] = (f16)(o.x - (float)hv[0]);
    hv[1] = (f16)o.y; lv[1] = (f16)(o.y - (float)hv[1]);
    hv[2] = (f16)o.z; lv[2] = (f16)(o.z - (float)hv[2]);
    hv[3] = (f16)o.w; lv[3] = (f16)(o.w - (float)hv[3]);
    // K-blocked write: ks = tid>>3, within-32 = (tid&7)*4
    const size_t xko = ((size_t)(tid >> 3) * Bn + row) * 32 + (tid & 7) * 4;
    *(f16x4*)(xhi + xko) = hv;
    *(f16x4*)(xlo + xko) = lv;
}

// ---------------- per-layer init ------------------------------------------
__global__ __launch_bounds__(256) void init_layer_kernel(
    float* __restrict__ outacc, int* __restrict__ rowlist, int* __restrict__ counts,
    long n, int maxslots)
{
    const long i = (long)blockIdx.x * blockDim.x + threadIdx.x;
    if (i < n) outacc[i] = 0.0f;
    if (i < maxslots) rowlist[i] = -1;
    if (i < T) counts[i] = 0;
}

// ---------------- router: logits, softmax, top-4 ---------------------------
__global__ __launch_bounds__(64) void router_kernel(
    const float* __restrict__ x, const float* __restrict__ Wr, int layer,
    float* __restrict__ gates, int* __restrict__ topi, int* __restrict__ counts)
{
    const int row = blockIdx.x, lane = threadIdx.x;
    __shared__ float xs[D];
    __shared__ float ls[T];
    for (int j = lane; j < D / 4; j += 64)
        *(float4*)&xs[j * 4] = *(const float4*)(x + (size_t)row * D + j * 4);
    __syncthreads();
    const int t = lane & 15, seg = lane >> 4;
    const float* wr = Wr + (size_t)layer * D * T;
    float acc = 0.0f;
    const int d0 = seg * 256;
    for (int j = 0; j < 256; ++j) {
        const int d = d0 + j;
        acc += xs[d] * wr[d * T + t];
    }
    acc += __shfl_down(acc, 32);
    acc += __shfl_down(acc, 16);
    if (lane < 16) ls[lane] = acc;
    __syncthreads();
    if (lane == 0) {
        float m = ls[0];
        for (int i = 1; i < 16; ++i) m = fmaxf(m, ls[i]);
        float p[16], ssum = 0.0f;
        for (int i = 0; i < 16; ++i) { p[i] = expf(ls[i] - m); ssum += p[i]; }
        const float inv = 1.0f / ssum;
        bool sel[16];
        for (int i = 0; i < 16; ++i) sel[i] = false;
        for (int j = 0; j < KSEL; ++j) {
            int best = 0; float bvv = -1e30f;
            for (int i = 0; i < 16; ++i)
                if (!sel[i] && ls[i] > bvv) { bvv = ls[i]; best = i; }
            sel[best] = true;
            topi[row * KSEL + j]  = best;
            gates[row * KSEL + j] = p[best] * inv;
            atomicAdd(&counts[best], 1);
        }
    }
}

// ---------------- scan: padded per-tile offsets ----------------------------
__global__ void scan_kernel(const int* __restrict__ counts, int* __restrict__ offp,
                            int* __restrict__ cur)
{
    if (threadIdx.x == 0) {
        int off = 0;
        for (int t = 0; t < T; ++t) {
            offp[t] = off;
            cur[t] = 0;
            off += ((counts[t] + PAD - 1) / PAD) * PAD;
        }
        offp[T] = off;
    }
}

// ---------------- scatter rows into tile slot lists ------------------------
__global__ __launch_bounds__(256) void scatter_kernel(
    const int* __restrict__ topi, const float* __restrict__ gates,
    const int* __restrict__ offp, int* __restrict__ cur,
    int* __restrict__ rowlist, float* __restrict__ slotgate, int Bn)
{
    const int row = blockIdx.x * blockDim.x + threadIdx.x;
    if (row >= Bn) return;
    for (int j = 0; j < KSEL; ++j) {
        const int t = topi[row * KSEL + j];
        const int pos = atomicAdd(&cur[t], 1);
        const int s = offp[t] + pos;
        rowlist[s] = row;
        slotgate[s] = gates[row * KSEL + j];
    }
}

// -------- transpose + hi/lo split: W(K,N) fp32 -> K-blocked f16 ------------
// Output layout: element (z, n, k) at z*K*N + (k>>5)*N*32 + n*32 + (k&31).
__global__ __launch_bounds__(256) void tspl_kernel(
    const float* __restrict__ W, f16* __restrict__ ohi, f16* __restrict__ olo,
    int K, int N)
{
    const size_t zoff = (size_t)blockIdx.z * K * N;
    const float* Wz = W + zoff;
    const int r0 = blockIdx.x * 32, c0 = blockIdx.y * 32;   // r0 = k, c0 = n
    __shared__ float tile[32][33];
    const int tr = threadIdx.x >> 3, tc = (threadIdx.x & 7) * 4;
    const float4 v = *(const float4*)(Wz + (size_t)(r0 + tr) * N + c0 + tc);
    tile[tr][tc + 0] = v.x; tile[tr][tc + 1] = v.y;
    tile[tr][tc + 2] = v.z; tile[tr][tc + 3] = v.w;
    __syncthreads();
    f16x4 h4, l4;
#pragma unroll
    for (int q = 0; q < 4; ++q) {
        const float f = tile[tc + q][tr];     // W[r0+tc+q][c0+tr]
        const f16 h = (f16)f;
        h4[q] = h; l4[q] = (f16)(f - (float)h);
    }
    // n = c0+tr, k = r0+tc..+3 ; ks = r0>>5 (tc<32), within-32 = tc..tc+3
    const size_t oidx = zoff + (size_t)(r0 >> 5) * N * 32 + (size_t)(c0 + tr) * 32 + tc;
    *(f16x4*)(ohi + oidx) = h4;
    *(f16x4*)(olo + oidx) = l4;
}

// ---------------- split-fp16 MFMA grouped GEMM (2-phase, coalesced) --------
// C(128x128) = A(128x1024) @ B(1024x128), 3-term hi/lo split, fp32 accum.
// All operands K-blocked [ks][row][32]; staging loads are contiguous 1KB per
// issue with a chunk-XOR (c ^ (row>>1)&3) folded into the SOURCE address;
// frag reads apply the same XOR. 2-D grid (x = slot-block, y = n-tile).
// mode 0: FFN GEMM1  - A gathered from xK planes via rowlist; gelu; HK out
// mode 1: FFN GEMM2  - A = HK planes (chunk-local); gate * y atomicAdd outF
// mode 2: head GEMM  - A = xK planes (row = slot); gelu; fp32 out (ld Ncols)
__global__ __launch_bounds__(256) void mfma_gemm_kernel(
    const f16* __restrict__ Ahi, const f16* __restrict__ Alo,
    const int* __restrict__ rowlist, const int* __restrict__ offp,
    const f16* __restrict__ Whi, const f16* __restrict__ Wlo,
    const float* __restrict__ biasbase, const float* __restrict__ slotgate,
    f16* __restrict__ Hhi, f16* __restrict__ Hlo,
    float* __restrict__ outF,
    int mode, int s0, int Ncols, int plainM, int ArowsA, int HrowsOut)
{
    const int slot0 = s0 + blockIdx.x * 128;
    const int n0 = blockIdx.y * 128;

    int t = 0;
    if (mode != 2) {
        if (slot0 >= offp[T]) return;
        while (t < T - 1 && offp[t + 1] <= slot0) ++t;   // bounded search
    } else {
        if (slot0 >= plainM) return;
    }
    const int tid = threadIdx.x;
    const int wave = tid >> 6, lane = tid & 63;

    // LDS: 2 buffers x [plane 0=Ahi 1=Alo 2=Bhi 3=Blo][row 128][32 halves]
    __shared__ f16 lds[2][4][128][32];       // 64 KB

    // 32 coalesced 1KB issues per K-step; wave w takes iss = w + 4*s.
    // Issue (plane b, sub j): LDS halves j*512 + lane*8; global source is the
    // 64B row-chunk of row (j*16 + lane>>2), chunk (lane&3) ^ ((row>>1)&3).
    const int rsub = lane >> 2, csub = lane & 3;
    const f16* gp[8];
    f16* lp[8];
    size_t str[8];
#pragma unroll
    for (int s = 0; s < 8; ++s) {
        const int iss = wave + 4 * s;
        const int b = iss >> 3, j = iss & 7;
        const int r = j * 16 + rsub;                 // LDS row 0..127
        const int cs = csub ^ ((r >> 1) & 3);        // source k-quad
        lp[s] = &lds[0][b][0][0] + (size_t)j * 512 + (size_t)lane * 8;
        if (b < 2) {
            const f16* plane = b ? Alo : Ahi;
            int row;
            if (mode == 0) {
                const int g = rowlist[slot0 + r];
                row = (g < 0 || g >= ArowsA) ? 0 : g;    // defensive clamp
            }
            else if (mode == 1) row = slot0 - s0 + r;
            else row = slot0 + r;
            gp[s] = plane + (size_t)row * 32 + (size_t)cs * 8;
            str[s] = (size_t)ArowsA * 32;
        } else {
            const f16* plane = (b == 3) ? Wlo : Whi;
            gp[s] = plane + (size_t)t * D * Ncols + (size_t)(n0 + r) * 32 + (size_t)cs * 8;
            str[s] = (size_t)Ncols * 32;
        }
    }

    f32x4 acc[4][4];
#pragma unroll
    for (int i = 0; i < 4; ++i)
#pragma unroll
        for (int j = 0; j < 4; ++j) acc[i][j] = (f32x4){0.f, 0.f, 0.f, 0.f};

    const int wr = wave >> 1, wc = wave & 1;
    const int qd = lane >> 4, m16 = lane & 15;
    const int swzh = (qd ^ ((m16 >> 1) & 3)) * 8;    // frag-read chunk XOR

    // ---- prologue: stage K-step 0 into buffer 0, drain, sync ----
#pragma unroll
    for (int s = 0; s < 8; ++s) { async16(gp[s], lp[s]); gp[s] += str[s]; }
    asm volatile("s_waitcnt vmcnt(0)" ::: "memory");
    __builtin_amdgcn_s_barrier();
    asm volatile("" ::: "memory");

    // ---- main loop: 31 pipelined steps (stage t+1 || compute t) ----
#pragma unroll 2
    for (int kt = 0; kt < 31; ++kt) {
        const int cur = kt & 1, nxt = cur ^ 1;
#pragma unroll
        for (int s = 0; s < 8; ++s) { async16(gp[s], lp[s] + (size_t)nxt * 16384); gp[s] += str[s]; }

        f16x8 ah[4], al[4], bh[4], bl[4];
#pragma unroll
        for (int i = 0; i < 4; ++i) {
            ah[i] = *(const f16x8*)&lds[cur][0][wr * 64 + i * 16 + m16][swzh];
            al[i] = *(const f16x8*)&lds[cur][1][wr * 64 + i * 16 + m16][swzh];
            bh[i] = *(const f16x8*)&lds[cur][2][wc * 64 + i * 16 + m16][swzh];
            bl[i] = *(const f16x8*)&lds[cur][3][wc * 64 + i * 16 + m16][swzh];
        }
        __builtin_amdgcn_s_setprio(1);
#pragma unroll
        for (int i = 0; i < 4; ++i)
#pragma unroll
            for (int j = 0; j < 4; ++j) {
                acc[i][j] = __builtin_amdgcn_mfma_f32_16x16x32_f16(ah[i], bh[j], acc[i][j], 0, 0, 0);
                acc[i][j] = __builtin_amdgcn_mfma_f32_16x16x32_f16(al[i], bh[j], acc[i][j], 0, 0, 0);
                acc[i][j] = __builtin_amdgcn_mfma_f32_16x16x32_f16(ah[i], bl[j], acc[i][j], 0, 0, 0);
            }
        __builtin_amdgcn_s_setprio(0);
        asm volatile("s_waitcnt vmcnt(0)" ::: "memory");
        __builtin_amdgcn_s_barrier();
        asm volatile("" ::: "memory");
    }

    // ---- epilogue compute: K-step 31 lives in buffer 1 ----
    {
        f16x8 ah[4], al[4], bh[4], bl[4];
#pragma unroll
        for (int i = 0; i < 4; ++i) {
            ah[i] = *(const f16x8*)&lds[1][0][wr * 64 + i * 16 + m16][swzh];
            al[i] = *(const f16x8*)&lds[1][1][wr * 64 + i * 16 + m16][swzh];
            bh[i] = *(const f16x8*)&lds[1][2][wc * 64 + i * 16 + m16][swzh];
            bl[i] = *(const f16x8*)&lds[1][3][wc * 64 + i * 16 + m16][swzh];
        }
        __builtin_amdgcn_s_setprio(1);
#pragma unroll
        for (int i = 0; i < 4; ++i)
#pragma unroll
            for (int j = 0; j < 4; ++j) {
                acc[i][j] = __builtin_amdgcn_mfma_f32_16x16x32_f16(ah[i], bh[j], acc[i][j], 0, 0, 0);
                acc[i][j] = __builtin_amdgcn_mfma_f32_16x16x32_f16(al[i], bh[j], acc[i][j], 0, 0, 0);
                acc[i][j] = __builtin_amdgcn_mfma_f32_16x16x32_f16(ah[i], bl[j], acc[i][j], 0, 0, 0);
            }
        __builtin_amdgcn_s_setprio(0);
    }

    float bj[4];
#pragma unroll
    for (int j = 0; j < 4; ++j)
        bj[j] = biasbase[(size_t)t * Ncols + n0 + wc * 64 + j * 16 + m16];

    if (mode == 0) {
        // write H in K-blocked layout [ks][ls][32] (consumed by GEMM2 staging)
#pragma unroll
        for (int i = 0; i < 4; ++i)
#pragma unroll
            for (int r = 0; r < 4; ++r) {
                const int lsg = slot0 - s0 + wr * 64 + i * 16 + qd * 4 + r;
#pragma unroll
                for (int j = 0; j < 4; ++j) {
                    const float v = gelu_f(acc[i][j][r] + bj[j]);
                    const f16 h = (f16)v;
                    const int col = n0 + wc * 64 + j * 16 + m16;
                    const size_t off = (size_t)(col >> 5) * ((size_t)HrowsOut * 32)
                                     + (size_t)lsg * 32 + (col & 31);
                    Hhi[off] = h;
                    Hlo[off] = (f16)(v - (float)h);
                }
            }
    } else if (mode == 1) {
#pragma unroll
        for (int i = 0; i < 4; ++i)
#pragma unroll
            for (int r = 0; r < 4; ++r) {
                const int s_ = slot0 + wr * 64 + i * 16 + qd * 4 + r;
                const int grow = rowlist[s_];
                if (grow < 0) continue;
                const float g = slotgate[s_];
                float* op = outF + (size_t)grow * 1024 + n0 + wc * 64 + m16;
#pragma unroll
                for (int j = 0; j < 4; ++j)
                    atomicAdd(op + j * 16, g * (acc[i][j][r] + bj[j]));
            }
    } else {
#pragma unroll
        for (int i = 0; i < 4; ++i)
#pragma unroll
            for (int r = 0; r < 4; ++r) {
                const int row = slot0 + wr * 64 + i * 16 + qd * 4 + r;
                float* op = outF + (size_t)row * Ncols + n0 + wc * 64 + m16;
#pragma unroll
                for (int j = 0; j < 4; ++j)
                    op[j * 16] = gelu_f(acc[i][j][r] + bj[j]);
            }
    }
}

// ---------------- residual + LN (+split x, K-blocked) ----------------------
__global__ __launch_bounds__(256) void ln_kernel(
    float* __restrict__ x, const float* __restrict__ res,
    const float* __restrict__ g, const float* __restrict__ b,
    f16* __restrict__ xhi, f16* __restrict__ xlo, int Bn)
{
    const int row = blockIdx.x, tid = threadIdx.x;
    const int d = tid << 2;
    float4 v = *(float4*)(x + (size_t)row * D + d);
    const float4 r = *(const float4*)(res + (size_t)row * D + d);
    v.x += r.x; v.y += r.y; v.z += r.z; v.w += r.w;
    __shared__ float red[256];
    red[tid] = v.x + v.y + v.z + v.w;
    __syncthreads();
    for (int st = 128; st > 0; st >>= 1) { if (tid < st) red[tid] += red[tid + st]; __syncthreads(); }
    const float mean = red[0] * (1.0f / 1024.0f);
    __syncthreads();
    const float dx0 = v.x - mean, dx1 = v.y - mean, dx2 = v.z - mean, dx3 = v.w - mean;
    red[tid] = dx0 * dx0 + dx1 * dx1 + dx2 * dx2 + dx3 * dx3;
    __syncthreads();
    for (int st = 128; st > 0; st >>= 1) { if (tid < st) red[tid] += red[tid + st]; __syncthreads(); }
    const float rstd = rsqrtf(red[0] * (1.0f / 1024.0f) + 1e-5f);
    const float4 g4 = *(const float4*)(g + d);
    const float4 b4 = *(const float4*)(b + d);
    float4 o;
    o.x = dx0 * rstd * g4.x + b4.x;
    o.y = dx1 * rstd * g4.y + b4.y;
    o.z = dx2 * rstd * g4.z + b4.z;
    o.w = dx3 * rstd * g4.w + b4.w;
    *(float4*)(x + (size_t)row * D + d) = o;
    f16x4 hv, lv;
    hv[0] = (f16)o.x; lv[0] = (f16)(o.x - (float)hv[0]);
    hv[1] = (f16)o.y; lv[1] = (f16)(o.y - (float)hv[1]);
    hv[2] = (f16)o.z; lv[2] = (f16)(o.z - (float)hv[2]);
    hv[3] = (f16)o.w; lv[3] = (f16)(o.w - (float)hv[3]);
    const size_t xko = ((size_t)(tid >> 3) * Bn + row) * 32 + (tid & 7) * 4;
    *(f16x4*)(xhi + xko) = hv;
    *(f16x4*)(xlo + xko) = lv;
}

// ---------------- final small head ----------------------------------------
__global__ __launch_bounds__(64) void head_final_kernel(
    const float* __restrict__ Hs, const float* __restrict__ Hd,
    const float* __restrict__ Ws2, const float* __restrict__ bs2,
    const float* __restrict__ Wd2, const float* __restrict__ bd2,
    float* __restrict__ outp)
{
    const int row = blockIdx.x, lane = threadIdx.x;
    float acc[11] = {};
    for (int m = 0; m < 8; ++m) {
        const int k = lane + 64 * m;
        const float hs = Hs[(size_t)row * 512 + k];
#pragma unroll
        for (int j = 0; j < 5; ++j) acc[j] += hs * Ws2[k * 5 + j];
        const float hd = Hd[(size_t)row * 512 + k];
#pragma unroll
        for (int j = 0; j < 6; ++j) acc[5 + j] += hd * Wd2[k * 6 + j];
    }
#pragma unroll
    for (int off = 32; off > 0; off >>= 1)
#pragma unroll
        for (int j = 0; j < 11; ++j) acc[j] += __shfl_down(acc[j], off);
    if (lane == 0) {
        for (int j = 0; j < 5; ++j) outp[(size_t)row * 11 + j] = acc[j] + bs2[j];
        for (int j = 0; j < 6; ++j) outp[(size_t)row * 11 + 5 + j] = acc[5 + j] + bd2[j];
    }
}

// ---------------------------------------------------------------------------
extern "C" void kernel_launch(void* const* d_in, const int* in_sizes, int n_in,
                              void* d_out, int out_size, void* d_ws, size_t ws_size,
                              hipStream_t stream)
{
    const int*   a    = (const int*)d_in[0];
    const int*   bI   = (const int*)d_in[1];
    const float* Win  = (const float*)d_in[2];
    const float* bin_ = (const float*)d_in[3];
    const float* g_in = (const float*)d_in[4];
    const float* b_ln = (const float*)d_in[5];
    const float* Wr   = (const float*)d_in[6];
    const float* W1   = (const float*)d_in[7];
    const float* b1   = (const float*)d_in[8];
    const float* W2   = (const float*)d_in[9];
    const float* b2   = (const float*)d_in[10];
    const float* g_l  = (const float*)d_in[11];
    const float* b_l  = (const float*)d_in[12];
    const float* Ws1  = (const float*)d_in[13];
    const float* bs1  = (const float*)d_in[14];
    const float* Ws2  = (const float*)d_in[15];
    const float* bs2  = (const float*)d_in[16];
    const float* Wd1  = (const float*)d_in[17];
    const float* bd1  = (const float*)d_in[18];
    const float* Wd2  = (const float*)d_in[19];
    const float* bd2  = (const float*)d_in[20];
    const int Bn = in_sizes[0];                 // 16384
    float* outF = (float*)d_out;

    const long maxslots = (long)Bn * KSEL + (long)T * PAD;  // 67584

    // ---- workspace carve (256 B aligned) ----
    char* p = (char*)d_ws;
    auto alloc = [&](size_t bytes) -> char* {
        char* r = p;
        p += (bytes + 255) & ~(size_t)255;
        return r;
    };
    float* x      = (float*)alloc((size_t)Bn * D * 4);
    f16*   xhi    = (f16*)alloc((size_t)Bn * D * 2);
    f16*   xlo    = (f16*)alloc((size_t)Bn * D * 2);
    float* outacc = (float*)alloc((size_t)Bn * D * 4);
    f16* WtAh = (f16*)alloc((size_t)T * D * D * 2);
    f16* WtAl = (f16*)alloc((size_t)T * D * D * 2);
    f16* WtBh = (f16*)alloc((size_t)T * D * D * 2);
    f16* WtBl = (f16*)alloc((size_t)T * D * D * 2);
    f16* Wtsh = (f16*)alloc((size_t)D * 512 * 2);
    f16* Wtsl = (f16*)alloc((size_t)D * 512 * 2);
    f16* Wtdh = (f16*)alloc((size_t)D * 512 * 2);
    f16* Wtdl = (f16*)alloc((size_t)D * 512 * 2);
    float* gates    = (float*)alloc((size_t)Bn * KSEL * 4);
    float* slotgate = (float*)alloc((size_t)maxslots * 4);
    int*   topi     = (int*)alloc((size_t)Bn * KSEL * 4);
    int*   rowlist  = (int*)alloc((size_t)maxslots * 4);
    int*   counts   = (int*)alloc(T * 4);
    int*   offp     = (int*)alloc((T + 1) * 4);
    int*   cur      = (int*)alloc(T * 4);
    const size_t used = (size_t)(p - (char*)d_ws);
    const size_t avail = (ws_size > used) ? (ws_size - used) : 0;

    // H chunk: Hhi+Hlo = 4096 B per slot. Heads later overlay fp32 Hs/Hd here.
    long hcap = (long)(avail / 4096);
    hcap &= ~(long)(PAD - 1);
    if (hcap > maxslots) hcap = maxslots;
    if (hcap < Bn) hcap = Bn;    // floor so head buffers (Bn*512*2 fp32) fit
    f16* Hhi = (f16*)p;
    f16* Hlo = Hhi + (size_t)hcap * D;
    float* Hs = (float*)p;
    float* Hd = Hs + (size_t)Bn * 512;
    const int nchunks = (int)((maxslots + hcap - 1) / hcap);
    const int mblocks = (int)(hcap / PAD);

    // ---- launches ----
    encode_kernel<<<Bn, 256, 0, stream>>>(a, bI, Win, bin_, g_in, b_ln, x, xhi, xlo, Bn);
    tspl_kernel<<<dim3(32, 16, 1), 256, 0, stream>>>(Ws1, Wtsh, Wtsl, D, 512);
    tspl_kernel<<<dim3(32, 16, 1), 256, 0, stream>>>(Wd1, Wtdh, Wtdl, D, 512);

    const long initn = (long)Bn * D;
    const int initblocks = (int)((initn + 255) / 256);
    for (int i = 0; i < 3; ++i) {
        init_layer_kernel<<<initblocks, 256, 0, stream>>>(outacc, rowlist, counts,
                                                          initn, (int)maxslots);
        router_kernel<<<Bn, 64, 0, stream>>>(x, Wr, i, gates, topi, counts);
        scan_kernel<<<1, 64, 0, stream>>>(counts, offp, cur);
        scatter_kernel<<<(Bn + 255) / 256, 256, 0, stream>>>(topi, gates, offp, cur,
                                                             rowlist, slotgate, Bn);
        tspl_kernel<<<dim3(32, 32, 16), 256, 0, stream>>>(W1 + (size_t)i * T * D * D,
                                                          WtAh, WtAl, D, D);
        tspl_kernel<<<dim3(32, 32, 16), 256, 0, stream>>>(W2 + (size_t)i * T * D * D,
                                                          WtBh, WtBl, D, D);
        const float* b1i = b1 + (size_t)i * T * D;
        const float* b2i = b2 + (size_t)i * T * D;
        for (int c = 0; c < nchunks; ++c) {
            const int s0 = (int)((long)c * hcap);
            dim3 grid(mblocks, D / 128);
            mfma_gemm_kernel<<<grid, 256, 0, stream>>>(
                xhi, xlo, rowlist, offp, WtAh, WtAl, b1i, nullptr,
                Hhi, Hlo, nullptr, 0, s0, D, 0, Bn, (int)hcap);
            mfma_gemm_kernel<<<grid, 256, 0, stream>>>(
                Hhi, Hlo, rowlist, offp, WtBh, WtBl, b2i, slotgate,
                nullptr, nullptr, outacc, 1, s0, D, 0, (int)hcap, (int)hcap);
        }
        ln_kernel<<<Bn, 256, 0, stream>>>(x, outacc, g_l + (size_t)i * D,
                                          b_l + (size_t)i * D, xhi, xlo, Bn);
    }

    // heads: Hs = gelu(x@Ws1+bs1), Hd = gelu(x@Wd1+bd1) via MFMA, then tiny head
    dim3 gh(Bn / 128, 512 / 128);
    mfma_gemm_kernel<<<gh, 256, 0, stream>>>(
        xhi, xlo, nullptr, nullptr, Wtsh, Wtsl, bs1, nullptr,
        nullptr, nullptr, Hs, 2, 0, 512, Bn, Bn, 0);
    mfma_gemm_kernel<<<gh, 256, 0, stream>>>(
        xhi, xlo, nullptr, nullptr, Wtdh, Wtdl, bd1, nullptr,
        nullptr, nullptr, Hd, 2, 0, 512, Bn, Bn, 0);
    head_final_kernel<<<Bn, 64, 0, stream>>>(Hs, Hd, Ws2, bs2, Wd2, bd2, outF);
}

// Round 5
// 5544.292 us; speedup vs baseline: 1.6325x; 1.3908x over previous
//
#include <hip/hip_runtime.h>
#include <math.h>

// ---------------------------------------------------------------------------
// PureTriXButterfly round 7: fast router.
// Round-6 profile: K-blocked GEMM staging worked (8692->7711us, GEMMs out of
// top-5); top-5 is now router_kernel at 773us x3 (VALU 4%, HBM 0.9%, 4.2M
// LDS bank conflicts) -- 200x off its 3.4us fp32-VALU roofline, pure latency
// serialization (1 row/block, serial 256-iter loop, strided Wr reads).
// New router: 128 rows/block, whole Wr layer slice (64KB) staged in LDS once,
// barrier-free k-loop, x chunks live in registers (the staging loads ARE the
// operands), 16 fp32 accumulators/thread, pair-reduce via shfl, identical
// top-4 tie-break + softmax ordering. Counts via LDS-local reduction.
// Everything else identical to the passing round-6 kernel.
// ---------------------------------------------------------------------------

constexpr int D    = 1024;
constexpr int T    = 16;
constexpr int KSEL = 4;
constexpr int PAD  = 128;   // slot padding per tile = GEMM M-tile

typedef _Float16 f16;
typedef f16 f16x8 __attribute__((ext_vector_type(8)));
typedef f16 f16x4 __attribute__((ext_vector_type(4)));
typedef float f32x4 __attribute__((ext_vector_type(4)));
typedef unsigned int u32;

__device__ __forceinline__ float gelu_f(float v) {
    return 0.5f * v * (1.0f + erff(v * 0.70710678118654752440f));
}

__device__ __forceinline__ void async16(const void* g, void* l) {
    __builtin_amdgcn_global_load_lds(
        (const __attribute__((address_space(1))) u32*)g,
        (__attribute__((address_space(3))) u32*)l, 16, 0, 0);
}

// ---------------- input encode: fourier -> @Win -> LN -> GELU (+split) -----
// xhi/xlo are stored K-blocked: element (row, k) at [k>>5][row][k&31].
__global__ __launch_bounds__(256) void encode_kernel(
    const int* __restrict__ A, const int* __restrict__ Bv,
    const float* __restrict__ Win, const float* __restrict__ bin_,
    const float* __restrict__ g_in, const float* __restrict__ b_ln,
    float* __restrict__ x, f16* __restrict__ xhi, f16* __restrict__ xlo, int Bn)
{
    const int row = blockIdx.x, tid = threadIdx.x;
    const float c = (float)(6.283185307179586476925286766559 / 16.0);
    float feat[32];
    const float xa = (float)A[row] * c;
    const float xb = (float)Bv[row] * c;
#pragma unroll
    for (int k = 0; k < 8; ++k) {
        const float f = (float)(1 << k);
        float aa = xa * f, ab = xb * f;
        feat[k]      = sinf(aa);
        feat[8 + k]  = cosf(aa);
        feat[16 + k] = sinf(ab);
        feat[24 + k] = cosf(ab);
    }
    const int d = tid << 2;
    float4 acc = *(const float4*)(bin_ + d);
#pragma unroll
    for (int f = 0; f < 32; ++f) {
        const float4 w = *(const float4*)(Win + (size_t)f * D + d);
        const float ff = feat[f];
        acc.x += ff * w.x; acc.y += ff * w.y; acc.z += ff * w.z; acc.w += ff * w.w;
    }
    __shared__ float red[256];
    red[tid] = acc.x + acc.y + acc.z + acc.w;
    __syncthreads();
    for (int st = 128; st > 0; st >>= 1) { if (tid < st) red[tid] += red[tid + st]; __syncthreads(); }
    const float mean = red[0] * (1.0f / 1024.0f);
    __syncthreads();
    float dx0 = acc.x - mean, dx1 = acc.y - mean, dx2 = acc.z - mean, dx3 = acc.w - mean;
    red[tid] = dx0 * dx0 + dx1 * dx1 + dx2 * dx2 + dx3 * dx3;
    __syncthreads();
    for (int st = 128; st > 0; st >>= 1) { if (tid < st) red[tid] += red[tid + st]; __syncthreads(); }
    const float rstd = rsqrtf(red[0] * (1.0f / 1024.0f) + 1e-5f);
    const float4 g4 = *(const float4*)(g_in + d);
    const float4 b4 = *(const float4*)(b_ln + d);
    float4 o;
    o.x = gelu_f(dx0 * rstd * g4.x + b4.x);
    o.y = gelu_f(dx1 * rstd * g4.y + b4.y);
    o.z = gelu_f(dx2 * rstd * g4.z + b4.z);
    o.w = gelu_f(dx3 * rstd * g4.w + b4.w);
    *(float4*)(x + (size_t)row * D + d) = o;
    f16x4 hv, lv;
    hv[0] = (f16)o.x; lv[0] = (f16)(o.x - (float)hv[0]);
    hv[1] = (f16)o.y; lv[1] = (f16)(o.y - (float)hv[1]);
    hv[2] = (f16)o.z; lv[2] = (f16)(o.z - (float)hv[2]);
    hv[3] = (f16)o.w; lv[3] = (f16)(o.w - (float)hv[3]);
    // K-blocked write: ks = tid>>3, within-32 = (tid&7)*4
    const size_t xko = ((size_t)(tid >> 3) * Bn + row) * 32 + (tid & 7) * 4;
    *(f16x4*)(xhi + xko) = hv;
    *(f16x4*)(xlo + xko) = lv;
}

// ---------------- per-layer init ------------------------------------------
__global__ __launch_bounds__(256) void init_layer_kernel(
    float* __restrict__ outacc, int* __restrict__ rowlist, int* __restrict__ counts,
    long n, int maxslots)
{
    const long i = (long)blockIdx.x * blockDim.x + threadIdx.x;
    if (i < n) outacc[i] = 0.0f;
    if (i < maxslots) rowlist[i] = -1;
    if (i < T) counts[i] = 0;
}

// ---------------- router: tiled logits GEMM + softmax + top-4 --------------
// 128 rows/block, 2 threads/row (tid = 2*row + half; half owns 16 dims of
// each 32-chunk). Whole Wr layer slice (1024x16 fp32 = 64KB) staged in LDS
// once; k-loop is barrier-free; x chunk float4s are kept in registers.
__global__ __launch_bounds__(256) void router_kernel(
    const float* __restrict__ x, const float* __restrict__ Wr, int layer,
    float* __restrict__ gates, int* __restrict__ topi, int* __restrict__ counts,
    int Bn)
{
    __shared__ float wrs[D][T];       // 64 KB
    __shared__ int lcnt[T];
    const int tid = threadIdx.x;
    const int r0 = blockIdx.x * 128;
    const int row = tid >> 1, half = tid & 1;
    if (tid < T) lcnt[tid] = 0;
    {
        const float4* src = (const float4*)(Wr + (size_t)layer * D * T);
        float4* dst = (float4*)&wrs[0][0];
        for (int i = tid; i < D * T / 4; i += 256) dst[i] = src[i];
    }
    __syncthreads();

    float acc[16];
#pragma unroll
    for (int t = 0; t < 16; ++t) acc[t] = 0.f;

    const float* xr = x + (size_t)(r0 + row) * D + half * 16;
    for (int kc = 0; kc < 32; ++kc) {
        float4 v[4];
#pragma unroll
        for (int q = 0; q < 4; ++q)
            v[q] = *(const float4*)(xr + kc * 32 + q * 4);
#pragma unroll
        for (int q = 0; q < 4; ++q) {
            const float xv4[4] = {v[q].x, v[q].y, v[q].z, v[q].w};
#pragma unroll
            for (int u = 0; u < 4; ++u) {
                const int d = kc * 32 + half * 16 + q * 4 + u;
                const float xv = xv4[u];
                const float4 w0 = *(const float4*)&wrs[d][0];
                const float4 w1 = *(const float4*)&wrs[d][4];
                const float4 w2 = *(const float4*)&wrs[d][8];
                const float4 w3 = *(const float4*)&wrs[d][12];
                acc[0]  += xv * w0.x; acc[1]  += xv * w0.y;
                acc[2]  += xv * w0.z; acc[3]  += xv * w0.w;
                acc[4]  += xv * w1.x; acc[5]  += xv * w1.y;
                acc[6]  += xv * w1.z; acc[7]  += xv * w1.w;
                acc[8]  += xv * w2.x; acc[9]  += xv * w2.y;
                acc[10] += xv * w2.z; acc[11] += xv * w2.w;
                acc[12] += xv * w3.x; acc[13] += xv * w3.y;
                acc[14] += xv * w3.z; acc[15] += xv * w3.w;
            }
        }
    }
    // combine the two halves of each row (even lane gets odd lane's partial)
#pragma unroll
    for (int t = 0; t < 16; ++t) acc[t] += __shfl_down(acc[t], 1);

    if (half == 0 && (r0 + row) < Bn) {
        const int grow = r0 + row;
        float m = acc[0];
        for (int i = 1; i < 16; ++i) m = fmaxf(m, acc[i]);
        float p[16], ssum = 0.0f;
        for (int i = 0; i < 16; ++i) { p[i] = expf(acc[i] - m); ssum += p[i]; }
        const float inv = 1.0f / ssum;
        bool sel[16];
        for (int i = 0; i < 16; ++i) sel[i] = false;
        for (int j = 0; j < KSEL; ++j) {
            int best = 0; float bvv = -1e30f;
            for (int i = 0; i < 16; ++i)
                if (!sel[i] && acc[i] > bvv) { bvv = acc[i]; best = i; }
            sel[best] = true;
            topi[grow * KSEL + j]  = best;
            gates[grow * KSEL + j] = p[best] * inv;
            atomicAdd(&lcnt[best], 1);
        }
    }
    __syncthreads();
    if (tid < T && lcnt[tid] > 0) atomicAdd(&counts[tid], lcnt[tid]);
}

// ---------------- scan: padded per-tile offsets ----------------------------
__global__ void scan_kernel(const int* __restrict__ counts, int* __restrict__ offp,
                            int* __restrict__ cur)
{
    if (threadIdx.x == 0) {
        int off = 0;
        for (int t = 0; t < T; ++t) {
            offp[t] = off;
            cur[t] = 0;
            off += ((counts[t] + PAD - 1) / PAD) * PAD;
        }
        offp[T] = off;
    }
}

// ---------------- scatter rows into tile slot lists ------------------------
__global__ __launch_bounds__(256) void scatter_kernel(
    const int* __restrict__ topi, const float* __restrict__ gates,
    const int* __restrict__ offp, int* __restrict__ cur,
    int* __restrict__ rowlist, float* __restrict__ slotgate, int Bn)
{
    const int row = blockIdx.x * blockDim.x + threadIdx.x;
    if (row >= Bn) return;
    for (int j = 0; j < KSEL; ++j) {
        const int t = topi[row * KSEL + j];
        const int pos = atomicAdd(&cur[t], 1);
        const int s = offp[t] + pos;
        rowlist[s] = row;
        slotgate[s] = gates[row * KSEL + j];
    }
}

// -------- transpose + hi/lo split: W(K,N) fp32 -> K-blocked f16 ------------
// Output layout: element (z, n, k) at z*K*N + (k>>5)*N*32 + n*32 + (k&31).
__global__ __launch_bounds__(256) void tspl_kernel(
    const float* __restrict__ W, f16* __restrict__ ohi, f16* __restrict__ olo,
    int K, int N)
{
    const size_t zoff = (size_t)blockIdx.z * K * N;
    const float* Wz = W + zoff;
    const int r0 = blockIdx.x * 32, c0 = blockIdx.y * 32;   // r0 = k, c0 = n
    __shared__ float tile[32][33];
    const int tr = threadIdx.x >> 3, tc = (threadIdx.x & 7) * 4;
    const float4 v = *(const float4*)(Wz + (size_t)(r0 + tr) * N + c0 + tc);
    tile[tr][tc + 0] = v.x; tile[tr][tc + 1] = v.y;
    tile[tr][tc + 2] = v.z; tile[tr][tc + 3] = v.w;
    __syncthreads();
    f16x4 h4, l4;
#pragma unroll
    for (int q = 0; q < 4; ++q) {
        const float f = tile[tc + q][tr];     // W[r0+tc+q][c0+tr]
        const f16 h = (f16)f;
        h4[q] = h; l4[q] = (f16)(f - (float)h);
    }
    // n = c0+tr, k = r0+tc..+3 ; ks = r0>>5 (tc<32), within-32 = tc..tc+3
    const size_t oidx = zoff + (size_t)(r0 >> 5) * N * 32 + (size_t)(c0 + tr) * 32 + tc;
    *(f16x4*)(ohi + oidx) = h4;
    *(f16x4*)(olo + oidx) = l4;
}

// ---------------- split-fp16 MFMA grouped GEMM (2-phase, coalesced) --------
// C(128x128) = A(128x1024) @ B(1024x128), 3-term hi/lo split, fp32 accum.
// All operands K-blocked [ks][row][32]; staging loads are contiguous 1KB per
// issue with a chunk-XOR (c ^ (row>>1)&3) folded into the SOURCE address;
// frag reads apply the same XOR. 2-D grid (x = slot-block, y = n-tile).
// mode 0: FFN GEMM1  - A gathered from xK planes via rowlist; gelu; HK out
// mode 1: FFN GEMM2  - A = HK planes (chunk-local); gate * y atomicAdd outF
// mode 2: head GEMM  - A = xK planes (row = slot); gelu; fp32 out (ld Ncols)
__global__ __launch_bounds__(256) void mfma_gemm_kernel(
    const f16* __restrict__ Ahi, const f16* __restrict__ Alo,
    const int* __restrict__ rowlist, const int* __restrict__ offp,
    const f16* __restrict__ Whi, const f16* __restrict__ Wlo,
    const float* __restrict__ biasbase, const float* __restrict__ slotgate,
    f16* __restrict__ Hhi, f16* __restrict__ Hlo,
    float* __restrict__ outF,
    int mode, int s0, int Ncols, int plainM, int ArowsA, int HrowsOut)
{
    const int slot0 = s0 + blockIdx.x * 128;
    const int n0 = blockIdx.y * 128;

    int t = 0;
    if (mode != 2) {
        if (slot0 >= offp[T]) return;
        while (t < T - 1 && offp[t + 1] <= slot0) ++t;   // bounded search
    } else {
        if (slot0 >= plainM) return;
    }
    const int tid = threadIdx.x;
    const int wave = tid >> 6, lane = tid & 63;

    // LDS: 2 buffers x [plane 0=Ahi 1=Alo 2=Bhi 3=Blo][row 128][32 halves]
    __shared__ f16 lds[2][4][128][32];       // 64 KB

    // 32 coalesced 1KB issues per K-step; wave w takes iss = w + 4*s.
    // Issue (plane b, sub j): LDS halves j*512 + lane*8; global source is the
    // 64B row-chunk of row (j*16 + lane>>2), chunk (lane&3) ^ ((row>>1)&3).
    const int rsub = lane >> 2, csub = lane & 3;
    const f16* gp[8];
    f16* lp[8];
    size_t str[8];
#pragma unroll
    for (int s = 0; s < 8; ++s) {
        const int iss = wave + 4 * s;
        const int b = iss >> 3, j = iss & 7;
        const int r = j * 16 + rsub;                 // LDS row 0..127
        const int cs = csub ^ ((r >> 1) & 3);        // source k-quad
        lp[s] = &lds[0][b][0][0] + (size_t)j * 512 + (size_t)lane * 8;
        if (b < 2) {
            const f16* plane = b ? Alo : Ahi;
            int row;
            if (mode == 0) {
                const int g = rowlist[slot0 + r];
                row = (g < 0 || g >= ArowsA) ? 0 : g;    // defensive clamp
            }
            else if (mode == 1) row = slot0 - s0 + r;
            else row = slot0 + r;
            gp[s] = plane + (size_t)row * 32 + (size_t)cs * 8;
            str[s] = (size_t)ArowsA * 32;
        } else {
            const f16* plane = (b == 3) ? Wlo : Whi;
            gp[s] = plane + (size_t)t * D * Ncols + (size_t)(n0 + r) * 32 + (size_t)cs * 8;
            str[s] = (size_t)Ncols * 32;
        }
    }

    f32x4 acc[4][4];
#pragma unroll
    for (int i = 0; i < 4; ++i)
#pragma unroll
        for (int j = 0; j < 4; ++j) acc[i][j] = (f32x4){0.f, 0.f, 0.f, 0.f};

    const int wr = wave >> 1, wc = wave & 1;
    const int qd = lane >> 4, m16 = lane & 15;
    const int swzh = (qd ^ ((m16 >> 1) & 3)) * 8;    // frag-read chunk XOR

    // ---- prologue: stage K-step 0 into buffer 0, drain, sync ----
#pragma unroll
    for (int s = 0; s < 8; ++s) { async16(gp[s], lp[s]); gp[s] += str[s]; }
    asm volatile("s_waitcnt vmcnt(0)" ::: "memory");
    __builtin_amdgcn_s_barrier();
    asm volatile("" ::: "memory");

    // ---- main loop: 31 pipelined steps (stage t+1 || compute t) ----
#pragma unroll 2
    for (int kt = 0; kt < 31; ++kt) {
        const int cur = kt & 1, nxt = cur ^ 1;
#pragma unroll
        for (int s = 0; s < 8; ++s) { async16(gp[s], lp[s] + (size_t)nxt * 16384); gp[s] += str[s]; }

        f16x8 ah[4], al[4], bh[4], bl[4];
#pragma unroll
        for (int i = 0; i < 4; ++i) {
            ah[i] = *(const f16x8*)&lds[cur][0][wr * 64 + i * 16 + m16][swzh];
            al[i] = *(const f16x8*)&lds[cur][1][wr * 64 + i * 16 + m16][swzh];
            bh[i] = *(const f16x8*)&lds[cur][2][wc * 64 + i * 16 + m16][swzh];
            bl[i] = *(const f16x8*)&lds[cur][3][wc * 64 + i * 16 + m16][swzh];
        }
        __builtin_amdgcn_s_setprio(1);
#pragma unroll
        for (int i = 0; i < 4; ++i)
#pragma unroll
            for (int j = 0; j < 4; ++j) {
                acc[i][j] = __builtin_amdgcn_mfma_f32_16x16x32_f16(ah[i], bh[j], acc[i][j], 0, 0, 0);
                acc[i][j] = __builtin_amdgcn_mfma_f32_16x16x32_f16(al[i], bh[j], acc[i][j], 0, 0, 0);
                acc[i][j] = __builtin_amdgcn_mfma_f32_16x16x32_f16(ah[i], bl[j], acc[i][j], 0, 0, 0);
            }
        __builtin_amdgcn_s_setprio(0);
        asm volatile("s_waitcnt vmcnt(0)" ::: "memory");
        __builtin_amdgcn_s_barrier();
        asm volatile("" ::: "memory");
    }

    // ---- epilogue compute: K-step 31 lives in buffer 1 ----
    {
        f16x8 ah[4], al[4], bh[4], bl[4];
#pragma unroll
        for (int i = 0; i < 4; ++i) {
            ah[i] = *(const f16x8*)&lds[1][0][wr * 64 + i * 16 + m16][swzh];
            al[i] = *(const f16x8*)&lds[1][1][wr * 64 + i * 16 + m16][swzh];
            bh[i] = *(const f16x8*)&lds[1][2][wc * 64 + i * 16 + m16][swzh];
            bl[i] = *(const f16x8*)&lds[1][3][wc * 64 + i * 16 + m16][swzh];
        }
        __builtin_amdgcn_s_setprio(1);
#pragma unroll
        for (int i = 0; i < 4; ++i)
#pragma unroll
            for (int j = 0; j < 4; ++j) {
                acc[i][j] = __builtin_amdgcn_mfma_f32_16x16x32_f16(ah[i], bh[j], acc[i][j], 0, 0, 0);
                acc[i][j] = __builtin_amdgcn_mfma_f32_16x16x32_f16(al[i], bh[j], acc[i][j], 0, 0, 0);
                acc[i][j] = __builtin_amdgcn_mfma_f32_16x16x32_f16(ah[i], bl[j], acc[i][j], 0, 0, 0);
            }
        __builtin_amdgcn_s_setprio(0);
    }

    float bj[4];
#pragma unroll
    for (int j = 0; j < 4; ++j)
        bj[j] = biasbase[(size_t)t * Ncols + n0 + wc * 64 + j * 16 + m16];

    if (mode == 0) {
        // write H in K-blocked layout [ks][ls][32] (consumed by GEMM2 staging)
#pragma unroll
        for (int i = 0; i < 4; ++i)
#pragma unroll
            for (int r = 0; r < 4; ++r) {
                const int lsg = slot0 - s0 + wr * 64 + i * 16 + qd * 4 + r;
#pragma unroll
                for (int j = 0; j < 4; ++j) {
                    const float v = gelu_f(acc[i][j][r] + bj[j]);
                    const f16 h = (f16)v;
                    const int col = n0 + wc * 64 + j * 16 + m16;
                    const size_t off = (size_t)(col >> 5) * ((size_t)HrowsOut * 32)
                                     + (size_t)lsg * 32 + (col & 31);
                    Hhi[off] = h;
                    Hlo[off] = (f16)(v - (float)h);
                }
            }
    } else if (mode == 1) {
#pragma unroll
        for (int i = 0; i < 4; ++i)
#pragma unroll
            for (int r = 0; r < 4; ++r) {
                const int s_ = slot0 + wr * 64 + i * 16 + qd * 4 + r;
                const int grow = rowlist[s_];
                if (grow < 0) continue;
                const float g = slotgate[s_];
                float* op = outF + (size_t)grow * 1024 + n0 + wc * 64 + m16;
#pragma unroll
                for (int j = 0; j < 4; ++j)
                    atomicAdd(op + j * 16, g * (acc[i][j][r] + bj[j]));
            }
    } else {
#pragma unroll
        for (int i = 0; i < 4; ++i)
#pragma unroll
            for (int r = 0; r < 4; ++r) {
                const int row = slot0 + wr * 64 + i * 16 + qd * 4 + r;
                float* op = outF + (size_t)row * Ncols + n0 + wc * 64 + m16;
#pragma unroll
                for (int j = 0; j < 4; ++j)
                    op[j * 16] = gelu_f(acc[i][j][r] + bj[j]);
            }
    }
}

// ---------------- residual + LN (+split x, K-blocked) ----------------------
__global__ __launch_bounds__(256) void ln_kernel(
    float* __restrict__ x, const float* __restrict__ res,
    const float* __restrict__ g, const float* __restrict__ b,
    f16* __restrict__ xhi, f16* __restrict__ xlo, int Bn)
{
    const int row = blockIdx.x, tid = threadIdx.x;
    const int d = tid << 2;
    float4 v = *(float4*)(x + (size_t)row * D + d);
    const float4 r = *(const float4*)(res + (size_t)row * D + d);
    v.x += r.x; v.y += r.y; v.z += r.z; v.w += r.w;
    __shared__ float red[256];
    red[tid] = v.x + v.y + v.z + v.w;
    __syncthreads();
    for (int st = 128; st > 0; st >>= 1) { if (tid < st) red[tid] += red[tid + st]; __syncthreads(); }
    const float mean = red[0] * (1.0f / 1024.0f);
    __syncthreads();
    const float dx0 = v.x - mean, dx1 = v.y - mean, dx2 = v.z - mean, dx3 = v.w - mean;
    red[tid] = dx0 * dx0 + dx1 * dx1 + dx2 * dx2 + dx3 * dx3;
    __syncthreads();
    for (int st = 128; st > 0; st >>= 1) { if (tid < st) red[tid] += red[tid + st]; __syncthreads(); }
    const float rstd = rsqrtf(red[0] * (1.0f / 1024.0f) + 1e-5f);
    const float4 g4 = *(const float4*)(g + d);
    const float4 b4 = *(const float4*)(b + d);
    float4 o;
    o.x = dx0 * rstd * g4.x + b4.x;
    o.y = dx1 * rstd * g4.y + b4.y;
    o.z = dx2 * rstd * g4.z + b4.z;
    o.w = dx3 * rstd * g4.w + b4.w;
    *(float4*)(x + (size_t)row * D + d) = o;
    f16x4 hv, lv;
    hv[0] = (f16)o.x; lv[0] = (f16)(o.x - (float)hv[0]);
    hv[1] = (f16)o.y; lv[1] = (f16)(o.y - (float)hv[1]);
    hv[2] = (f16)o.z; lv[2] = (f16)(o.z - (float)hv[2]);
    hv[3] = (f16)o.w; lv[3] = (f16)(o.w - (float)hv[3]);
    const size_t xko = ((size_t)(tid >> 3) * Bn + row) * 32 + (tid & 7) * 4;
    *(f16x4*)(xhi + xko) = hv;
    *(f16x4*)(xlo + xko) = lv;
}

// ---------------- final small head ----------------------------------------
__global__ __launch_bounds__(64) void head_final_kernel(
    const float* __restrict__ Hs, const float* __restrict__ Hd,
    const float* __restrict__ Ws2, const float* __restrict__ bs2,
    const float* __restrict__ Wd2, const float* __restrict__ bd2,
    float* __restrict__ outp)
{
    const int row = blockIdx.x, lane = threadIdx.x;
    float acc[11] = {};
    for (int m = 0; m < 8; ++m) {
        const int k = lane + 64 * m;
        const float hs = Hs[(size_t)row * 512 + k];
#pragma unroll
        for (int j = 0; j < 5; ++j) acc[j] += hs * Ws2[k * 5 + j];
        const float hd = Hd[(size_t)row * 512 + k];
#pragma unroll
        for (int j = 0; j < 6; ++j) acc[5 + j] += hd * Wd2[k * 6 + j];
    }
#pragma unroll
    for (int off = 32; off > 0; off >>= 1)
#pragma unroll
        for (int j = 0; j < 11; ++j) acc[j] += __shfl_down(acc[j], off);
    if (lane == 0) {
        for (int j = 0; j < 5; ++j) outp[(size_t)row * 11 + j] = acc[j] + bs2[j];
        for (int j = 0; j < 6; ++j) outp[(size_t)row * 11 + 5 + j] = acc[5 + j] + bd2[j];
    }
}

// ---------------------------------------------------------------------------
extern "C" void kernel_launch(void* const* d_in, const int* in_sizes, int n_in,
                              void* d_out, int out_size, void* d_ws, size_t ws_size,
                              hipStream_t stream)
{
    const int*   a    = (const int*)d_in[0];
    const int*   bI   = (const int*)d_in[1];
    const float* Win  = (const float*)d_in[2];
    const float* bin_ = (const float*)d_in[3];
    const float* g_in = (const float*)d_in[4];
    const float* b_ln = (const float*)d_in[5];
    const float* Wr   = (const float*)d_in[6];
    const float* W1   = (const float*)d_in[7];
    const float* b1   = (const float*)d_in[8];
    const float* W2   = (const float*)d_in[9];
    const float* b2   = (const float*)d_in[10];
    const float* g_l  = (const float*)d_in[11];
    const float* b_l  = (const float*)d_in[12];
    const float* Ws1  = (const float*)d_in[13];
    const float* bs1  = (const float*)d_in[14];
    const float* Ws2  = (const float*)d_in[15];
    const float* bs2  = (const float*)d_in[16];
    const float* Wd1  = (const float*)d_in[17];
    const float* bd1  = (const float*)d_in[18];
    const float* Wd2  = (const float*)d_in[19];
    const float* bd2  = (const float*)d_in[20];
    const int Bn = in_sizes[0];                 // 16384
    float* outF = (float*)d_out;

    const long maxslots = (long)Bn * KSEL + (long)T * PAD;  // 67584

    // ---- workspace carve (256 B aligned) ----
    char* p = (char*)d_ws;
    auto alloc = [&](size_t bytes) -> char* {
        char* r = p;
        p += (bytes + 255) & ~(size_t)255;
        return r;
    };
    float* x      = (float*)alloc((size_t)Bn * D * 4);
    f16*   xhi    = (f16*)alloc((size_t)Bn * D * 2);
    f16*   xlo    = (f16*)alloc((size_t)Bn * D * 2);
    float* outacc = (float*)alloc((size_t)Bn * D * 4);
    f16* WtAh = (f16*)alloc((size_t)T * D * D * 2);
    f16* WtAl = (f16*)alloc((size_t)T * D * D * 2);
    f16* WtBh = (f16*)alloc((size_t)T * D * D * 2);
    f16* WtBl = (f16*)alloc((size_t)T * D * D * 2);
    f16* Wtsh = (f16*)alloc((size_t)D * 512 * 2);
    f16* Wtsl = (f16*)alloc((size_t)D * 512 * 2);
    f16* Wtdh = (f16*)alloc((size_t)D * 512 * 2);
    f16* Wtdl = (f16*)alloc((size_t)D * 512 * 2);
    float* gates    = (float*)alloc((size_t)Bn * KSEL * 4);
    float* slotgate = (float*)alloc((size_t)maxslots * 4);
    int*   topi     = (int*)alloc((size_t)Bn * KSEL * 4);
    int*   rowlist  = (int*)alloc((size_t)maxslots * 4);
    int*   counts   = (int*)alloc(T * 4);
    int*   offp     = (int*)alloc((T + 1) * 4);
    int*   cur      = (int*)alloc(T * 4);
    const size_t used = (size_t)(p - (char*)d_ws);
    const size_t avail = (ws_size > used) ? (ws_size - used) : 0;

    // H chunk: Hhi+Hlo = 4096 B per slot. Heads later overlay fp32 Hs/Hd here.
    long hcap = (long)(avail / 4096);
    hcap &= ~(long)(PAD - 1);
    if (hcap > maxslots) hcap = maxslots;
    if (hcap < Bn) hcap = Bn;    // floor so head buffers (Bn*512*2 fp32) fit
    f16* Hhi = (f16*)p;
    f16* Hlo = Hhi + (size_t)hcap * D;
    float* Hs = (float*)p;
    float* Hd = Hs + (size_t)Bn * 512;
    const int nchunks = (int)((maxslots + hcap - 1) / hcap);
    const int mblocks = (int)(hcap / PAD);

    // ---- launches ----
    encode_kernel<<<Bn, 256, 0, stream>>>(a, bI, Win, bin_, g_in, b_ln, x, xhi, xlo, Bn);
    tspl_kernel<<<dim3(32, 16, 1), 256, 0, stream>>>(Ws1, Wtsh, Wtsl, D, 512);
    tspl_kernel<<<dim3(32, 16, 1), 256, 0, stream>>>(Wd1, Wtdh, Wtdl, D, 512);

    const long initn = (long)Bn * D;
    const int initblocks = (int)((initn + 255) / 256);
    for (int i = 0; i < 3; ++i) {
        init_layer_kernel<<<initblocks, 256, 0, stream>>>(outacc, rowlist, counts,
                                                          initn, (int)maxslots);
        router_kernel<<<(Bn + 127) / 128, 256, 0, stream>>>(x, Wr, i, gates, topi,
                                                            counts, Bn);
        scan_kernel<<<1, 64, 0, stream>>>(counts, offp, cur);
        scatter_kernel<<<(Bn + 255) / 256, 256, 0, stream>>>(topi, gates, offp, cur,
                                                             rowlist, slotgate, Bn);
        tspl_kernel<<<dim3(32, 32, 16), 256, 0, stream>>>(W1 + (size_t)i * T * D * D,
                                                          WtAh, WtAl, D, D);
        tspl_kernel<<<dim3(32, 32, 16), 256, 0, stream>>>(W2 + (size_t)i * T * D * D,
                                                          WtBh, WtBl, D, D);
        const float* b1i = b1 + (size_t)i * T * D;
        const float* b2i = b2 + (size_t)i * T * D;
        for (int c = 0; c < nchunks; ++c) {
            const int s0 = (int)((long)c * hcap);
            dim3 grid(mblocks, D / 128);
            mfma_gemm_kernel<<<grid, 256, 0, stream>>>(
                xhi, xlo, rowlist, offp, WtAh, WtAl, b1i, nullptr,
                Hhi, Hlo, nullptr, 0, s0, D, 0, Bn, (int)hcap);
            mfma_gemm_kernel<<<grid, 256, 0, stream>>>(
                Hhi, Hlo, rowlist, offp, WtBh, WtBl, b2i, slotgate,
                nullptr, nullptr, outacc, 1, s0, D, 0, (int)hcap, (int)hcap);
        }
        ln_kernel<<<Bn, 256, 0, stream>>>(x, outacc, g_l + (size_t)i * D,
                                          b_l + (size_t)i * D, xhi, xlo, Bn);
    }

    // heads: Hs = gelu(x@Ws1+bs1), Hd = gelu(x@Wd1+bd1) via MFMA, then tiny head
    dim3 gh(Bn / 128, 512 / 128);
    mfma_gemm_kernel<<<gh, 256, 0, stream>>>(
        xhi, xlo, nullptr, nullptr, Wtsh, Wtsl, bs1, nullptr,
        nullptr, nullptr, Hs, 2, 0, 512, Bn, Bn, 0);
    mfma_gemm_kernel<<<gh, 256, 0, stream>>>(
        xhi, xlo, nullptr, nullptr, Wtdh, Wtdl, bd1, nullptr,
        nullptr, nullptr, Hd, 2, 0, 512, Bn, Bn, 0);
    head_final_kernel<<<Bn, 64, 0, stream>>>(Hs, Hd, Ws2, bs2, Wd2, bd2, outF);
}

// Round 6
// 5057.905 us; speedup vs baseline: 1.7895x; 1.0962x over previous
//
#include <hip/hip_runtime.h>
#include <math.h>

// ---------------------------------------------------------------------------
// PureTriXButterfly round 8: n-tile-major dispatch for A-panel reuse.
// Round-7 profile: GEMMs at 657us with FETCH_SIZE 2.28GB = the 277MB A panel
// re-read 8x (slot-block was the fastest grid dim, so all 528 slot-blocks
// stream the whole A for n-tile 0, evicting L3 before n-tile 1). Fix: swap
// grid dims so the 8 n-tiles of each slot-panel dispatch consecutively and
// share the A panel via L2/L3. Two-line kernel change + launcher grids.
// Everything else identical to the passing round-7 kernel.
// ---------------------------------------------------------------------------

constexpr int D    = 1024;
constexpr int T    = 16;
constexpr int KSEL = 4;
constexpr int PAD  = 128;   // slot padding per tile = GEMM M-tile

typedef _Float16 f16;
typedef f16 f16x8 __attribute__((ext_vector_type(8)));
typedef f16 f16x4 __attribute__((ext_vector_type(4)));
typedef float f32x4 __attribute__((ext_vector_type(4)));
typedef unsigned int u32;

__device__ __forceinline__ float gelu_f(float v) {
    return 0.5f * v * (1.0f + erff(v * 0.70710678118654752440f));
}

__device__ __forceinline__ void async16(const void* g, void* l) {
    __builtin_amdgcn_global_load_lds(
        (const __attribute__((address_space(1))) u32*)g,
        (__attribute__((address_space(3))) u32*)l, 16, 0, 0);
}

// ---------------- input encode: fourier -> @Win -> LN -> GELU (+split) -----
// xhi/xlo are stored K-blocked: element (row, k) at [k>>5][row][k&31].
__global__ __launch_bounds__(256) void encode_kernel(
    const int* __restrict__ A, const int* __restrict__ Bv,
    const float* __restrict__ Win, const float* __restrict__ bin_,
    const float* __restrict__ g_in, const float* __restrict__ b_ln,
    float* __restrict__ x, f16* __restrict__ xhi, f16* __restrict__ xlo, int Bn)
{
    const int row = blockIdx.x, tid = threadIdx.x;
    const float c = (float)(6.283185307179586476925286766559 / 16.0);
    float feat[32];
    const float xa = (float)A[row] * c;
    const float xb = (float)Bv[row] * c;
#pragma unroll
    for (int k = 0; k < 8; ++k) {
        const float f = (float)(1 << k);
        float aa = xa * f, ab = xb * f;
        feat[k]      = sinf(aa);
        feat[8 + k]  = cosf(aa);
        feat[16 + k] = sinf(ab);
        feat[24 + k] = cosf(ab);
    }
    const int d = tid << 2;
    float4 acc = *(const float4*)(bin_ + d);
#pragma unroll
    for (int f = 0; f < 32; ++f) {
        const float4 w = *(const float4*)(Win + (size_t)f * D + d);
        const float ff = feat[f];
        acc.x += ff * w.x; acc.y += ff * w.y; acc.z += ff * w.z; acc.w += ff * w.w;
    }
    __shared__ float red[256];
    red[tid] = acc.x + acc.y + acc.z + acc.w;
    __syncthreads();
    for (int st = 128; st > 0; st >>= 1) { if (tid < st) red[tid] += red[tid + st]; __syncthreads(); }
    const float mean = red[0] * (1.0f / 1024.0f);
    __syncthreads();
    float dx0 = acc.x - mean, dx1 = acc.y - mean, dx2 = acc.z - mean, dx3 = acc.w - mean;
    red[tid] = dx0 * dx0 + dx1 * dx1 + dx2 * dx2 + dx3 * dx3;
    __syncthreads();
    for (int st = 128; st > 0; st >>= 1) { if (tid < st) red[tid] += red[tid + st]; __syncthreads(); }
    const float rstd = rsqrtf(red[0] * (1.0f / 1024.0f) + 1e-5f);
    const float4 g4 = *(const float4*)(g_in + d);
    const float4 b4 = *(const float4*)(b_ln + d);
    float4 o;
    o.x = gelu_f(dx0 * rstd * g4.x + b4.x);
    o.y = gelu_f(dx1 * rstd * g4.y + b4.y);
    o.z = gelu_f(dx2 * rstd * g4.z + b4.z);
    o.w = gelu_f(dx3 * rstd * g4.w + b4.w);
    *(float4*)(x + (size_t)row * D + d) = o;
    f16x4 hv, lv;
    hv[0] = (f16)o.x; lv[0] = (f16)(o.x - (float)hv[0]);
    hv[1] = (f16)o.y; lv[1] = (f16)(o.y - (float)hv[1]);
    hv[2] = (f16)o.z; lv[2] = (f16)(o.z - (float)hv[2]);
    hv[3] = (f16)o.w; lv[3] = (f16)(o.w - (float)hv[3]);
    // K-blocked write: ks = tid>>3, within-32 = (tid&7)*4
    const size_t xko = ((size_t)(tid >> 3) * Bn + row) * 32 + (tid & 7) * 4;
    *(f16x4*)(xhi + xko) = hv;
    *(f16x4*)(xlo + xko) = lv;
}

// ---------------- per-layer init ------------------------------------------
__global__ __launch_bounds__(256) void init_layer_kernel(
    float* __restrict__ outacc, int* __restrict__ rowlist, int* __restrict__ counts,
    long n, int maxslots)
{
    const long i = (long)blockIdx.x * blockDim.x + threadIdx.x;
    if (i < n) outacc[i] = 0.0f;
    if (i < maxslots) rowlist[i] = -1;
    if (i < T) counts[i] = 0;
}

// ---------------- router: tiled logits GEMM + softmax + top-4 --------------
// 128 rows/block, 2 threads/row (tid = 2*row + half; half owns 16 dims of
// each 32-chunk). Whole Wr layer slice (1024x16 fp32 = 64KB) staged in LDS
// once; k-loop is barrier-free; x chunk float4s are kept in registers.
__global__ __launch_bounds__(256) void router_kernel(
    const float* __restrict__ x, const float* __restrict__ Wr, int layer,
    float* __restrict__ gates, int* __restrict__ topi, int* __restrict__ counts,
    int Bn)
{
    __shared__ float wrs[D][T];       // 64 KB
    __shared__ int lcnt[T];
    const int tid = threadIdx.x;
    const int r0 = blockIdx.x * 128;
    const int row = tid >> 1, half = tid & 1;
    if (tid < T) lcnt[tid] = 0;
    {
        const float4* src = (const float4*)(Wr + (size_t)layer * D * T);
        float4* dst = (float4*)&wrs[0][0];
        for (int i = tid; i < D * T / 4; i += 256) dst[i] = src[i];
    }
    __syncthreads();

    float acc[16];
#pragma unroll
    for (int t = 0; t < 16; ++t) acc[t] = 0.f;

    const float* xr = x + (size_t)(r0 + row) * D + half * 16;
    for (int kc = 0; kc < 32; ++kc) {
        float4 v[4];
#pragma unroll
        for (int q = 0; q < 4; ++q)
            v[q] = *(const float4*)(xr + kc * 32 + q * 4);
#pragma unroll
        for (int q = 0; q < 4; ++q) {
            const float xv4[4] = {v[q].x, v[q].y, v[q].z, v[q].w};
#pragma unroll
            for (int u = 0; u < 4; ++u) {
                const int d = kc * 32 + half * 16 + q * 4 + u;
                const float xv = xv4[u];
                const float4 w0 = *(const float4*)&wrs[d][0];
                const float4 w1 = *(const float4*)&wrs[d][4];
                const float4 w2 = *(const float4*)&wrs[d][8];
                const float4 w3 = *(const float4*)&wrs[d][12];
                acc[0]  += xv * w0.x; acc[1]  += xv * w0.y;
                acc[2]  += xv * w0.z; acc[3]  += xv * w0.w;
                acc[4]  += xv * w1.x; acc[5]  += xv * w1.y;
                acc[6]  += xv * w1.z; acc[7]  += xv * w1.w;
                acc[8]  += xv * w2.x; acc[9]  += xv * w2.y;
                acc[10] += xv * w2.z; acc[11] += xv * w2.w;
                acc[12] += xv * w3.x; acc[13] += xv * w3.y;
                acc[14] += xv * w3.z; acc[15] += xv * w3.w;
            }
        }
    }
    // combine the two halves of each row (even lane gets odd lane's partial)
#pragma unroll
    for (int t = 0; t < 16; ++t) acc[t] += __shfl_down(acc[t], 1);

    if (half == 0 && (r0 + row) < Bn) {
        const int grow = r0 + row;
        float m = acc[0];
        for (int i = 1; i < 16; ++i) m = fmaxf(m, acc[i]);
        float p[16], ssum = 0.0f;
        for (int i = 0; i < 16; ++i) { p[i] = expf(acc[i] - m); ssum += p[i]; }
        const float inv = 1.0f / ssum;
        bool sel[16];
        for (int i = 0; i < 16; ++i) sel[i] = false;
        for (int j = 0; j < KSEL; ++j) {
            int best = 0; float bvv = -1e30f;
            for (int i = 0; i < 16; ++i)
                if (!sel[i] && acc[i] > bvv) { bvv = acc[i]; best = i; }
            sel[best] = true;
            topi[grow * KSEL + j]  = best;
            gates[grow * KSEL + j] = p[best] * inv;
            atomicAdd(&lcnt[best], 1);
        }
    }
    __syncthreads();
    if (tid < T && lcnt[tid] > 0) atomicAdd(&counts[tid], lcnt[tid]);
}

// ---------------- scan: padded per-tile offsets ----------------------------
__global__ void scan_kernel(const int* __restrict__ counts, int* __restrict__ offp,
                            int* __restrict__ cur)
{
    if (threadIdx.x == 0) {
        int off = 0;
        for (int t = 0; t < T; ++t) {
            offp[t] = off;
            cur[t] = 0;
            off += ((counts[t] + PAD - 1) / PAD) * PAD;
        }
        offp[T] = off;
    }
}

// ---------------- scatter rows into tile slot lists ------------------------
__global__ __launch_bounds__(256) void scatter_kernel(
    const int* __restrict__ topi, const float* __restrict__ gates,
    const int* __restrict__ offp, int* __restrict__ cur,
    int* __restrict__ rowlist, float* __restrict__ slotgate, int Bn)
{
    const int row = blockIdx.x * blockDim.x + threadIdx.x;
    if (row >= Bn) return;
    for (int j = 0; j < KSEL; ++j) {
        const int t = topi[row * KSEL + j];
        const int pos = atomicAdd(&cur[t], 1);
        const int s = offp[t] + pos;
        rowlist[s] = row;
        slotgate[s] = gates[row * KSEL + j];
    }
}

// -------- transpose + hi/lo split: W(K,N) fp32 -> K-blocked f16 ------------
// Output layout: element (z, n, k) at z*K*N + (k>>5)*N*32 + n*32 + (k&31).
__global__ __launch_bounds__(256) void tspl_kernel(
    const float* __restrict__ W, f16* __restrict__ ohi, f16* __restrict__ olo,
    int K, int N)
{
    const size_t zoff = (size_t)blockIdx.z * K * N;
    const float* Wz = W + zoff;
    const int r0 = blockIdx.x * 32, c0 = blockIdx.y * 32;   // r0 = k, c0 = n
    __shared__ float tile[32][33];
    const int tr = threadIdx.x >> 3, tc = (threadIdx.x & 7) * 4;
    const float4 v = *(const float4*)(Wz + (size_t)(r0 + tr) * N + c0 + tc);
    tile[tr][tc + 0] = v.x; tile[tr][tc + 1] = v.y;
    tile[tr][tc + 2] = v.z; tile[tr][tc + 3] = v.w;
    __syncthreads();
    f16x4 h4, l4;
#pragma unroll
    for (int q = 0; q < 4; ++q) {
        const float f = tile[tc + q][tr];     // W[r0+tc+q][c0+tr]
        const f16 h = (f16)f;
        h4[q] = h; l4[q] = (f16)(f - (float)h);
    }
    // n = c0+tr, k = r0+tc..+3 ; ks = r0>>5 (tc<32), within-32 = tc..tc+3
    const size_t oidx = zoff + (size_t)(r0 >> 5) * N * 32 + (size_t)(c0 + tr) * 32 + tc;
    *(f16x4*)(ohi + oidx) = h4;
    *(f16x4*)(olo + oidx) = l4;
}

// ---------------- split-fp16 MFMA grouped GEMM (2-phase, coalesced) --------
// C(128x128) = A(128x1024) @ B(1024x128), 3-term hi/lo split, fp32 accum.
// All operands K-blocked [ks][row][32]; staging loads are contiguous 1KB per
// issue with a chunk-XOR (c ^ (row>>1)&3) folded into the SOURCE address;
// frag reads apply the same XOR.
// Grid: x = n-tile (FAST, for A-panel L2/L3 reuse), y = slot-block.
// mode 0: FFN GEMM1  - A gathered from xK planes via rowlist; gelu; HK out
// mode 1: FFN GEMM2  - A = HK planes (chunk-local); gate * y atomicAdd outF
// mode 2: head GEMM  - A = xK planes (row = slot); gelu; fp32 out (ld Ncols)
__global__ __launch_bounds__(256) void mfma_gemm_kernel(
    const f16* __restrict__ Ahi, const f16* __restrict__ Alo,
    const int* __restrict__ rowlist, const int* __restrict__ offp,
    const f16* __restrict__ Whi, const f16* __restrict__ Wlo,
    const float* __restrict__ biasbase, const float* __restrict__ slotgate,
    f16* __restrict__ Hhi, f16* __restrict__ Hlo,
    float* __restrict__ outF,
    int mode, int s0, int Ncols, int plainM, int ArowsA, int HrowsOut)
{
    const int slot0 = s0 + blockIdx.y * 128;   // slot-panel (slow dim)
    const int n0 = blockIdx.x * 128;           // n-tile (fast dim)

    int t = 0;
    if (mode != 2) {
        if (slot0 >= offp[T]) return;
        while (t < T - 1 && offp[t + 1] <= slot0) ++t;   // bounded search
    } else {
        if (slot0 >= plainM) return;
    }
    const int tid = threadIdx.x;
    const int wave = tid >> 6, lane = tid & 63;

    // LDS: 2 buffers x [plane 0=Ahi 1=Alo 2=Bhi 3=Blo][row 128][32 halves]
    __shared__ f16 lds[2][4][128][32];       // 64 KB

    // 32 coalesced 1KB issues per K-step; wave w takes iss = w + 4*s.
    // Issue (plane b, sub j): LDS halves j*512 + lane*8; global source is the
    // 64B row-chunk of row (j*16 + lane>>2), chunk (lane&3) ^ ((row>>1)&3).
    const int rsub = lane >> 2, csub = lane & 3;
    const f16* gp[8];
    f16* lp[8];
    size_t str[8];
#pragma unroll
    for (int s = 0; s < 8; ++s) {
        const int iss = wave + 4 * s;
        const int b = iss >> 3, j = iss & 7;
        const int r = j * 16 + rsub;                 // LDS row 0..127
        const int cs = csub ^ ((r >> 1) & 3);        // source k-quad
        lp[s] = &lds[0][b][0][0] + (size_t)j * 512 + (size_t)lane * 8;
        if (b < 2) {
            const f16* plane = b ? Alo : Ahi;
            int row;
            if (mode == 0) {
                const int g = rowlist[slot0 + r];
                row = (g < 0 || g >= ArowsA) ? 0 : g;    // defensive clamp
            }
            else if (mode == 1) row = slot0 - s0 + r;
            else row = slot0 + r;
            gp[s] = plane + (size_t)row * 32 + (size_t)cs * 8;
            str[s] = (size_t)ArowsA * 32;
        } else {
            const f16* plane = (b == 3) ? Wlo : Whi;
            gp[s] = plane + (size_t)t * D * Ncols + (size_t)(n0 + r) * 32 + (size_t)cs * 8;
            str[s] = (size_t)Ncols * 32;
        }
    }

    f32x4 acc[4][4];
#pragma unroll
    for (int i = 0; i < 4; ++i)
#pragma unroll
        for (int j = 0; j < 4; ++j) acc[i][j] = (f32x4){0.f, 0.f, 0.f, 0.f};

    const int wr = wave >> 1, wc = wave & 1;
    const int qd = lane >> 4, m16 = lane & 15;
    const int swzh = (qd ^ ((m16 >> 1) & 3)) * 8;    // frag-read chunk XOR

    // ---- prologue: stage K-step 0 into buffer 0, drain, sync ----
#pragma unroll
    for (int s = 0; s < 8; ++s) { async16(gp[s], lp[s]); gp[s] += str[s]; }
    asm volatile("s_waitcnt vmcnt(0)" ::: "memory");
    __builtin_amdgcn_s_barrier();
    asm volatile("" ::: "memory");

    // ---- main loop: 31 pipelined steps (stage t+1 || compute t) ----
#pragma unroll 2
    for (int kt = 0; kt < 31; ++kt) {
        const int cur = kt & 1, nxt = cur ^ 1;
#pragma unroll
        for (int s = 0; s < 8; ++s) { async16(gp[s], lp[s] + (size_t)nxt * 16384); gp[s] += str[s]; }

        f16x8 ah[4], al[4], bh[4], bl[4];
#pragma unroll
        for (int i = 0; i < 4; ++i) {
            ah[i] = *(const f16x8*)&lds[cur][0][wr * 64 + i * 16 + m16][swzh];
            al[i] = *(const f16x8*)&lds[cur][1][wr * 64 + i * 16 + m16][swzh];
            bh[i] = *(const f16x8*)&lds[cur][2][wc * 64 + i * 16 + m16][swzh];
            bl[i] = *(const f16x8*)&lds[cur][3][wc * 64 + i * 16 + m16][swzh];
        }
        __builtin_amdgcn_s_setprio(1);
#pragma unroll
        for (int i = 0; i < 4; ++i)
#pragma unroll
            for (int j = 0; j < 4; ++j) {
                acc[i][j] = __builtin_amdgcn_mfma_f32_16x16x32_f16(ah[i], bh[j], acc[i][j], 0, 0, 0);
                acc[i][j] = __builtin_amdgcn_mfma_f32_16x16x32_f16(al[i], bh[j], acc[i][j], 0, 0, 0);
                acc[i][j] = __builtin_amdgcn_mfma_f32_16x16x32_f16(ah[i], bl[j], acc[i][j], 0, 0, 0);
            }
        __builtin_amdgcn_s_setprio(0);
        asm volatile("s_waitcnt vmcnt(0)" ::: "memory");
        __builtin_amdgcn_s_barrier();
        asm volatile("" ::: "memory");
    }

    // ---- epilogue compute: K-step 31 lives in buffer 1 ----
    {
        f16x8 ah[4], al[4], bh[4], bl[4];
#pragma unroll
        for (int i = 0; i < 4; ++i) {
            ah[i] = *(const f16x8*)&lds[1][0][wr * 64 + i * 16 + m16][swzh];
            al[i] = *(const f16x8*)&lds[1][1][wr * 64 + i * 16 + m16][swzh];
            bh[i] = *(const f16x8*)&lds[1][2][wc * 64 + i * 16 + m16][swzh];
            bl[i] = *(const f16x8*)&lds[1][3][wc * 64 + i * 16 + m16][swzh];
        }
        __builtin_amdgcn_s_setprio(1);
#pragma unroll
        for (int i = 0; i < 4; ++i)
#pragma unroll
            for (int j = 0; j < 4; ++j) {
                acc[i][j] = __builtin_amdgcn_mfma_f32_16x16x32_f16(ah[i], bh[j], acc[i][j], 0, 0, 0);
                acc[i][j] = __builtin_amdgcn_mfma_f32_16x16x32_f16(al[i], bh[j], acc[i][j], 0, 0, 0);
                acc[i][j] = __builtin_amdgcn_mfma_f32_16x16x32_f16(ah[i], bl[j], acc[i][j], 0, 0, 0);
            }
        __builtin_amdgcn_s_setprio(0);
    }

    float bj[4];
#pragma unroll
    for (int j = 0; j < 4; ++j)
        bj[j] = biasbase[(size_t)t * Ncols + n0 + wc * 64 + j * 16 + m16];

    if (mode == 0) {
        // write H in K-blocked layout [ks][ls][32] (consumed by GEMM2 staging)
#pragma unroll
        for (int i = 0; i < 4; ++i)
#pragma unroll
            for (int r = 0; r < 4; ++r) {
                const int lsg = slot0 - s0 + wr * 64 + i * 16 + qd * 4 + r;
#pragma unroll
                for (int j = 0; j < 4; ++j) {
                    const float v = gelu_f(acc[i][j][r] + bj[j]);
                    const f16 h = (f16)v;
                    const int col = n0 + wc * 64 + j * 16 + m16;
                    const size_t off = (size_t)(col >> 5) * ((size_t)HrowsOut * 32)
                                     + (size_t)lsg * 32 + (col & 31);
                    Hhi[off] = h;
                    Hlo[off] = (f16)(v - (float)h);
                }
            }
    } else if (mode == 1) {
#pragma unroll
        for (int i = 0; i < 4; ++i)
#pragma unroll
            for (int r = 0; r < 4; ++r) {
                const int s_ = slot0 + wr * 64 + i * 16 + qd * 4 + r;
                const int grow = rowlist[s_];
                if (grow < 0) continue;
                const float g = slotgate[s_];
                float* op = outF + (size_t)grow * 1024 + n0 + wc * 64 + m16;
#pragma unroll
                for (int j = 0; j < 4; ++j)
                    atomicAdd(op + j * 16, g * (acc[i][j][r] + bj[j]));
            }
    } else {
#pragma unroll
        for (int i = 0; i < 4; ++i)
#pragma unroll
            for (int r = 0; r < 4; ++r) {
                const int row = slot0 + wr * 64 + i * 16 + qd * 4 + r;
                float* op = outF + (size_t)row * Ncols + n0 + wc * 64 + m16;
#pragma unroll
                for (int j = 0; j < 4; ++j)
                    op[j * 16] = gelu_f(acc[i][j][r] + bj[j]);
            }
    }
}

// ---------------- residual + LN (+split x, K-blocked) ----------------------
__global__ __launch_bounds__(256) void ln_kernel(
    float* __restrict__ x, const float* __restrict__ res,
    const float* __restrict__ g, const float* __restrict__ b,
    f16* __restrict__ xhi, f16* __restrict__ xlo, int Bn)
{
    const int row = blockIdx.x, tid = threadIdx.x;
    const int d = tid << 2;
    float4 v = *(float4*)(x + (size_t)row * D + d);
    const float4 r = *(const float4*)(res + (size_t)row * D + d);
    v.x += r.x; v.y += r.y; v.z += r.z; v.w += r.w;
    __shared__ float red[256];
    red[tid] = v.x + v.y + v.z + v.w;
    __syncthreads();
    for (int st = 128; st > 0; st >>= 1) { if (tid < st) red[tid] += red[tid + st]; __syncthreads(); }
    const float mean = red[0] * (1.0f / 1024.0f);
    __syncthreads();
    const float dx0 = v.x - mean, dx1 = v.y - mean, dx2 = v.z - mean, dx3 = v.w - mean;
    red[tid] = dx0 * dx0 + dx1 * dx1 + dx2 * dx2 + dx3 * dx3;
    __syncthreads();
    for (int st = 128; st > 0; st >>= 1) { if (tid < st) red[tid] += red[tid + st]; __syncthreads(); }
    const float rstd = rsqrtf(red[0] * (1.0f / 1024.0f) + 1e-5f);
    const float4 g4 = *(const float4*)(g + d);
    const float4 b4 = *(const float4*)(b + d);
    float4 o;
    o.x = dx0 * rstd * g4.x + b4.x;
    o.y = dx1 * rstd * g4.y + b4.y;
    o.z = dx2 * rstd * g4.z + b4.z;
    o.w = dx3 * rstd * g4.w + b4.w;
    *(float4*)(x + (size_t)row * D + d) = o;
    f16x4 hv, lv;
    hv[0] = (f16)o.x; lv[0] = (f16)(o.x - (float)hv[0]);
    hv[1] = (f16)o.y; lv[1] = (f16)(o.y - (float)hv[1]);
    hv[2] = (f16)o.z; lv[2] = (f16)(o.z - (float)hv[2]);
    hv[3] = (f16)o.w; lv[3] = (f16)(o.w - (float)hv[3]);
    const size_t xko = ((size_t)(tid >> 3) * Bn + row) * 32 + (tid & 7) * 4;
    *(f16x4*)(xhi + xko) = hv;
    *(f16x4*)(xlo + xko) = lv;
}

// ---------------- final small head ----------------------------------------
__global__ __launch_bounds__(64) void head_final_kernel(
    const float* __restrict__ Hs, const float* __restrict__ Hd,
    const float* __restrict__ Ws2, const float* __restrict__ bs2,
    const float* __restrict__ Wd2, const float* __restrict__ bd2,
    float* __restrict__ outp)
{
    const int row = blockIdx.x, lane = threadIdx.x;
    float acc[11] = {};
    for (int m = 0; m < 8; ++m) {
        const int k = lane + 64 * m;
        const float hs = Hs[(size_t)row * 512 + k];
#pragma unroll
        for (int j = 0; j < 5; ++j) acc[j] += hs * Ws2[k * 5 + j];
        const float hd = Hd[(size_t)row * 512 + k];
#pragma unroll
        for (int j = 0; j < 6; ++j) acc[5 + j] += hd * Wd2[k * 6 + j];
    }
#pragma unroll
    for (int off = 32; off > 0; off >>= 1)
#pragma unroll
        for (int j = 0; j < 11; ++j) acc[j] += __shfl_down(acc[j], off);
    if (lane == 0) {
        for (int j = 0; j < 5; ++j) outp[(size_t)row * 11 + j] = acc[j] + bs2[j];
        for (int j = 0; j < 6; ++j) outp[(size_t)row * 11 + 5 + j] = acc[5 + j] + bd2[j];
    }
}

// ---------------------------------------------------------------------------
extern "C" void kernel_launch(void* const* d_in, const int* in_sizes, int n_in,
                              void* d_out, int out_size, void* d_ws, size_t ws_size,
                              hipStream_t stream)
{
    const int*   a    = (const int*)d_in[0];
    const int*   bI   = (const int*)d_in[1];
    const float* Win  = (const float*)d_in[2];
    const float* bin_ = (const float*)d_in[3];
    const float* g_in = (const float*)d_in[4];
    const float* b_ln = (const float*)d_in[5];
    const float* Wr   = (const float*)d_in[6];
    const float* W1   = (const float*)d_in[7];
    const float* b1   = (const float*)d_in[8];
    const float* W2   = (const float*)d_in[9];
    const float* b2   = (const float*)d_in[10];
    const float* g_l  = (const float*)d_in[11];
    const float* b_l  = (const float*)d_in[12];
    const float* Ws1  = (const float*)d_in[13];
    const float* bs1  = (const float*)d_in[14];
    const float* Ws2  = (const float*)d_in[15];
    const float* bs2  = (const float*)d_in[16];
    const float* Wd1  = (const float*)d_in[17];
    const float* bd1  = (const float*)d_in[18];
    const float* Wd2  = (const float*)d_in[19];
    const float* bd2  = (const float*)d_in[20];
    const int Bn = in_sizes[0];                 // 16384
    float* outF = (float*)d_out;

    const long maxslots = (long)Bn * KSEL + (long)T * PAD;  // 67584

    // ---- workspace carve (256 B aligned) ----
    char* p = (char*)d_ws;
    auto alloc = [&](size_t bytes) -> char* {
        char* r = p;
        p += (bytes + 255) & ~(size_t)255;
        return r;
    };
    float* x      = (float*)alloc((size_t)Bn * D * 4);
    f16*   xhi    = (f16*)alloc((size_t)Bn * D * 2);
    f16*   xlo    = (f16*)alloc((size_t)Bn * D * 2);
    float* outacc = (float*)alloc((size_t)Bn * D * 4);
    f16* WtAh = (f16*)alloc((size_t)T * D * D * 2);
    f16* WtAl = (f16*)alloc((size_t)T * D * D * 2);
    f16* WtBh = (f16*)alloc((size_t)T * D * D * 2);
    f16* WtBl = (f16*)alloc((size_t)T * D * D * 2);
    f16* Wtsh = (f16*)alloc((size_t)D * 512 * 2);
    f16* Wtsl = (f16*)alloc((size_t)D * 512 * 2);
    f16* Wtdh = (f16*)alloc((size_t)D * 512 * 2);
    f16* Wtdl = (f16*)alloc((size_t)D * 512 * 2);
    float* gates    = (float*)alloc((size_t)Bn * KSEL * 4);
    float* slotgate = (float*)alloc((size_t)maxslots * 4);
    int*   topi     = (int*)alloc((size_t)Bn * KSEL * 4);
    int*   rowlist  = (int*)alloc((size_t)maxslots * 4);
    int*   counts   = (int*)alloc(T * 4);
    int*   offp     = (int*)alloc((T + 1) * 4);
    int*   cur      = (int*)alloc(T * 4);
    const size_t used = (size_t)(p - (char*)d_ws);
    const size_t avail = (ws_size > used) ? (ws_size - used) : 0;

    // H chunk: Hhi+Hlo = 4096 B per slot. Heads later overlay fp32 Hs/Hd here.
    long hcap = (long)(avail / 4096);
    hcap &= ~(long)(PAD - 1);
    if (hcap > maxslots) hcap = maxslots;
    if (hcap < Bn) hcap = Bn;    // floor so head buffers (Bn*512*2 fp32) fit
    f16* Hhi = (f16*)p;
    f16* Hlo = Hhi + (size_t)hcap * D;
    float* Hs = (float*)p;
    float* Hd = Hs + (size_t)Bn * 512;
    const int nchunks = (int)((maxslots + hcap - 1) / hcap);
    const int mblocks = (int)(hcap / PAD);

    // ---- launches ----
    encode_kernel<<<Bn, 256, 0, stream>>>(a, bI, Win, bin_, g_in, b_ln, x, xhi, xlo, Bn);
    tspl_kernel<<<dim3(32, 16, 1), 256, 0, stream>>>(Ws1, Wtsh, Wtsl, D, 512);
    tspl_kernel<<<dim3(32, 16, 1), 256, 0, stream>>>(Wd1, Wtdh, Wtdl, D, 512);

    const long initn = (long)Bn * D;
    const int initblocks = (int)((initn + 255) / 256);
    for (int i = 0; i < 3; ++i) {
        init_layer_kernel<<<initblocks, 256, 0, stream>>>(outacc, rowlist, counts,
                                                          initn, (int)maxslots);
        router_kernel<<<(Bn + 127) / 128, 256, 0, stream>>>(x, Wr, i, gates, topi,
                                                            counts, Bn);
        scan_kernel<<<1, 64, 0, stream>>>(counts, offp, cur);
        scatter_kernel<<<(Bn + 255) / 256, 256, 0, stream>>>(topi, gates, offp, cur,
                                                             rowlist, slotgate, Bn);
        tspl_kernel<<<dim3(32, 32, 16), 256, 0, stream>>>(W1 + (size_t)i * T * D * D,
                                                          WtAh, WtAl, D, D);
        tspl_kernel<<<dim3(32, 32, 16), 256, 0, stream>>>(W2 + (size_t)i * T * D * D,
                                                          WtBh, WtBl, D, D);
        const float* b1i = b1 + (size_t)i * T * D;
        const float* b2i = b2 + (size_t)i * T * D;
        for (int c = 0; c < nchunks; ++c) {
            const int s0 = (int)((long)c * hcap);
            dim3 grid(D / 128, mblocks);   // n-tile fast, slot-panel slow
            mfma_gemm_kernel<<<grid, 256, 0, stream>>>(
                xhi, xlo, rowlist, offp, WtAh, WtAl, b1i, nullptr,
                Hhi, Hlo, nullptr, 0, s0, D, 0, Bn, (int)hcap);
            mfma_gemm_kernel<<<grid, 256, 0, stream>>>(
                Hhi, Hlo, rowlist, offp, WtBh, WtBl, b2i, slotgate,
                nullptr, nullptr, outacc, 1, s0, D, 0, (int)hcap, (int)hcap);
        }
        ln_kernel<<<Bn, 256, 0, stream>>>(x, outacc, g_l + (size_t)i * D,
                                          b_l + (size_t)i * D, xhi, xlo, Bn);
    }

    // heads: Hs = gelu(x@Ws1+bs1), Hd = gelu(x@Wd1+bd1) via MFMA, then tiny head
    dim3 gh(512 / 128, Bn / 128);          // n-tile fast, row-panel slow
    mfma_gemm_kernel<<<gh, 256, 0, stream>>>(
        xhi, xlo, nullptr, nullptr, Wtsh, Wtsl, bs1, nullptr,
        nullptr, nullptr, Hs, 2, 0, 512, Bn, Bn, 0);
    mfma_gemm_kernel<<<gh, 256, 0, stream>>>(
        xhi, xlo, nullptr, nullptr, Wtdh, Wtdl, bd1, nullptr,
        nullptr, nullptr, Hd, 2, 0, 512, Bn, Bn, 0);
    head_final_kernel<<<Bn, 64, 0, stream>>>(Hs, Hd, Ws2, bs2, Wd2, bd2, outF);
}

// Round 7
// 4460.733 us; speedup vs baseline: 2.0291x; 1.1339x over previous
//
#include <hip/hip_runtime.h>
#include <math.h>

// ---------------------------------------------------------------------------
// PureTriXButterfly round 9: XCD-chunked block remap (T1) for A-panel reuse.
// Round-8 post-mortem: grid-dim swap made the 8 n-tiles of a slot-panel
// adjacent in dispatch order, but MI355X round-robins consecutive blocks
// across 8 XCDs -> the 8 blocks sharing an A-panel sit on 8 different L2s,
// and FETCH_SIZE stayed ~2GB (8x re-fetch at the EA level; only L3 absorbed).
// Fix: 1-D grid + bijective XCD remap wgid=(bid%8)*(nwg/8)+bid/8 with n-tile
// fastest in logical order -> each XCD owns complete slot-panels; A-panel hits
// its L2 once, W panel set (4MB/slot-panel) is L2-resident and reused across
// slot-panels of the same expert tile. Everything else identical to round 8.
// ---------------------------------------------------------------------------

constexpr int D    = 1024;
constexpr int T    = 16;
constexpr int KSEL = 4;
constexpr int PAD  = 128;   // slot padding per tile = GEMM M-tile

typedef _Float16 f16;
typedef f16 f16x8 __attribute__((ext_vector_type(8)));
typedef f16 f16x4 __attribute__((ext_vector_type(4)));
typedef float f32x4 __attribute__((ext_vector_type(4)));
typedef unsigned int u32;

__device__ __forceinline__ float gelu_f(float v) {
    return 0.5f * v * (1.0f + erff(v * 0.70710678118654752440f));
}

__device__ __forceinline__ void async16(const void* g, void* l) {
    __builtin_amdgcn_global_load_lds(
        (const __attribute__((address_space(1))) u32*)g,
        (__attribute__((address_space(3))) u32*)l, 16, 0, 0);
}

// ---------------- input encode: fourier -> @Win -> LN -> GELU (+split) -----
// xhi/xlo are stored K-blocked: element (row, k) at [k>>5][row][k&31].
__global__ __launch_bounds__(256) void encode_kernel(
    const int* __restrict__ A, const int* __restrict__ Bv,
    const float* __restrict__ Win, const float* __restrict__ bin_,
    const float* __restrict__ g_in, const float* __restrict__ b_ln,
    float* __restrict__ x, f16* __restrict__ xhi, f16* __restrict__ xlo, int Bn)
{
    const int row = blockIdx.x, tid = threadIdx.x;
    const float c = (float)(6.283185307179586476925286766559 / 16.0);
    float feat[32];
    const float xa = (float)A[row] * c;
    const float xb = (float)Bv[row] * c;
#pragma unroll
    for (int k = 0; k < 8; ++k) {
        const float f = (float)(1 << k);
        float aa = xa * f, ab = xb * f;
        feat[k]      = sinf(aa);
        feat[8 + k]  = cosf(aa);
        feat[16 + k] = sinf(ab);
        feat[24 + k] = cosf(ab);
    }
    const int d = tid << 2;
    float4 acc = *(const float4*)(bin_ + d);
#pragma unroll
    for (int f = 0; f < 32; ++f) {
        const float4 w = *(const float4*)(Win + (size_t)f * D + d);
        const float ff = feat[f];
        acc.x += ff * w.x; acc.y += ff * w.y; acc.z += ff * w.z; acc.w += ff * w.w;
    }
    __shared__ float red[256];
    red[tid] = acc.x + acc.y + acc.z + acc.w;
    __syncthreads();
    for (int st = 128; st > 0; st >>= 1) { if (tid < st) red[tid] += red[tid + st]; __syncthreads(); }
    const float mean = red[0] * (1.0f / 1024.0f);
    __syncthreads();
    float dx0 = acc.x - mean, dx1 = acc.y - mean, dx2 = acc.z - mean, dx3 = acc.w - mean;
    red[tid] = dx0 * dx0 + dx1 * dx1 + dx2 * dx2 + dx3 * dx3;
    __syncthreads();
    for (int st = 128; st > 0; st >>= 1) { if (tid < st) red[tid] += red[tid + st]; __syncthreads(); }
    const float rstd = rsqrtf(red[0] * (1.0f / 1024.0f) + 1e-5f);
    const float4 g4 = *(const float4*)(g_in + d);
    const float4 b4 = *(const float4*)(b_ln + d);
    float4 o;
    o.x = gelu_f(dx0 * rstd * g4.x + b4.x);
    o.y = gelu_f(dx1 * rstd * g4.y + b4.y);
    o.z = gelu_f(dx2 * rstd * g4.z + b4.z);
    o.w = gelu_f(dx3 * rstd * g4.w + b4.w);
    *(float4*)(x + (size_t)row * D + d) = o;
    f16x4 hv, lv;
    hv[0] = (f16)o.x; lv[0] = (f16)(o.x - (float)hv[0]);
    hv[1] = (f16)o.y; lv[1] = (f16)(o.y - (float)hv[1]);
    hv[2] = (f16)o.z; lv[2] = (f16)(o.z - (float)hv[2]);
    hv[3] = (f16)o.w; lv[3] = (f16)(o.w - (float)hv[3]);
    // K-blocked write: ks = tid>>3, within-32 = (tid&7)*4
    const size_t xko = ((size_t)(tid >> 3) * Bn + row) * 32 + (tid & 7) * 4;
    *(f16x4*)(xhi + xko) = hv;
    *(f16x4*)(xlo + xko) = lv;
}

// ---------------- per-layer init ------------------------------------------
__global__ __launch_bounds__(256) void init_layer_kernel(
    float* __restrict__ outacc, int* __restrict__ rowlist, int* __restrict__ counts,
    long n, int maxslots)
{
    const long i = (long)blockIdx.x * blockDim.x + threadIdx.x;
    if (i < n) outacc[i] = 0.0f;
    if (i < maxslots) rowlist[i] = -1;
    if (i < T) counts[i] = 0;
}

// ---------------- router: tiled logits GEMM + softmax + top-4 --------------
// 128 rows/block, 2 threads/row (tid = 2*row + half; half owns 16 dims of
// each 32-chunk). Whole Wr layer slice (1024x16 fp32 = 64KB) staged in LDS
// once; k-loop is barrier-free; x chunk float4s are kept in registers.
__global__ __launch_bounds__(256) void router_kernel(
    const float* __restrict__ x, const float* __restrict__ Wr, int layer,
    float* __restrict__ gates, int* __restrict__ topi, int* __restrict__ counts,
    int Bn)
{
    __shared__ float wrs[D][T];       // 64 KB
    __shared__ int lcnt[T];
    const int tid = threadIdx.x;
    const int r0 = blockIdx.x * 128;
    const int row = tid >> 1, half = tid & 1;
    if (tid < T) lcnt[tid] = 0;
    {
        const float4* src = (const float4*)(Wr + (size_t)layer * D * T);
        float4* dst = (float4*)&wrs[0][0];
        for (int i = tid; i < D * T / 4; i += 256) dst[i] = src[i];
    }
    __syncthreads();

    float acc[16];
#pragma unroll
    for (int t = 0; t < 16; ++t) acc[t] = 0.f;

    const float* xr = x + (size_t)(r0 + row) * D + half * 16;
    for (int kc = 0; kc < 32; ++kc) {
        float4 v[4];
#pragma unroll
        for (int q = 0; q < 4; ++q)
            v[q] = *(const float4*)(xr + kc * 32 + q * 4);
#pragma unroll
        for (int q = 0; q < 4; ++q) {
            const float xv4[4] = {v[q].x, v[q].y, v[q].z, v[q].w};
#pragma unroll
            for (int u = 0; u < 4; ++u) {
                const int d = kc * 32 + half * 16 + q * 4 + u;
                const float xv = xv4[u];
                const float4 w0 = *(const float4*)&wrs[d][0];
                const float4 w1 = *(const float4*)&wrs[d][4];
                const float4 w2 = *(const float4*)&wrs[d][8];
                const float4 w3 = *(const float4*)&wrs[d][12];
                acc[0]  += xv * w0.x; acc[1]  += xv * w0.y;
                acc[2]  += xv * w0.z; acc[3]  += xv * w0.w;
                acc[4]  += xv * w1.x; acc[5]  += xv * w1.y;
                acc[6]  += xv * w1.z; acc[7]  += xv * w1.w;
                acc[8]  += xv * w2.x; acc[9]  += xv * w2.y;
                acc[10] += xv * w2.z; acc[11] += xv * w2.w;
                acc[12] += xv * w3.x; acc[13] += xv * w3.y;
                acc[14] += xv * w3.z; acc[15] += xv * w3.w;
            }
        }
    }
    // combine the two halves of each row (even lane gets odd lane's partial)
#pragma unroll
    for (int t = 0; t < 16; ++t) acc[t] += __shfl_down(acc[t], 1);

    if (half == 0 && (r0 + row) < Bn) {
        const int grow = r0 + row;
        float m = acc[0];
        for (int i = 1; i < 16; ++i) m = fmaxf(m, acc[i]);
        float p[16], ssum = 0.0f;
        for (int i = 0; i < 16; ++i) { p[i] = expf(acc[i] - m); ssum += p[i]; }
        const float inv = 1.0f / ssum;
        bool sel[16];
        for (int i = 0; i < 16; ++i) sel[i] = false;
        for (int j = 0; j < KSEL; ++j) {
            int best = 0; float bvv = -1e30f;
            for (int i = 0; i < 16; ++i)
                if (!sel[i] && acc[i] > bvv) { bvv = acc[i]; best = i; }
            sel[best] = true;
            topi[grow * KSEL + j]  = best;
            gates[grow * KSEL + j] = p[best] * inv;
            atomicAdd(&lcnt[best], 1);
        }
    }
    __syncthreads();
    if (tid < T && lcnt[tid] > 0) atomicAdd(&counts[tid], lcnt[tid]);
}

// ---------------- scan: padded per-tile offsets ----------------------------
__global__ void scan_kernel(const int* __restrict__ counts, int* __restrict__ offp,
                            int* __restrict__ cur)
{
    if (threadIdx.x == 0) {
        int off = 0;
        for (int t = 0; t < T; ++t) {
            offp[t] = off;
            cur[t] = 0;
            off += ((counts[t] + PAD - 1) / PAD) * PAD;
        }
        offp[T] = off;
    }
}

// ---------------- scatter rows into tile slot lists ------------------------
__global__ __launch_bounds__(256) void scatter_kernel(
    const int* __restrict__ topi, const float* __restrict__ gates,
    const int* __restrict__ offp, int* __restrict__ cur,
    int* __restrict__ rowlist, float* __restrict__ slotgate, int Bn)
{
    const int row = blockIdx.x * blockDim.x + threadIdx.x;
    if (row >= Bn) return;
    for (int j = 0; j < KSEL; ++j) {
        const int t = topi[row * KSEL + j];
        const int pos = atomicAdd(&cur[t], 1);
        const int s = offp[t] + pos;
        rowlist[s] = row;
        slotgate[s] = gates[row * KSEL + j];
    }
}

// -------- transpose + hi/lo split: W(K,N) fp32 -> K-blocked f16 ------------
// Output layout: element (z, n, k) at z*K*N + (k>>5)*N*32 + n*32 + (k&31).
__global__ __launch_bounds__(256) void tspl_kernel(
    const float* __restrict__ W, f16* __restrict__ ohi, f16* __restrict__ olo,
    int K, int N)
{
    const size_t zoff = (size_t)blockIdx.z * K * N;
    const float* Wz = W + zoff;
    const int r0 = blockIdx.x * 32, c0 = blockIdx.y * 32;   // r0 = k, c0 = n
    __shared__ float tile[32][33];
    const int tr = threadIdx.x >> 3, tc = (threadIdx.x & 7) * 4;
    const float4 v = *(const float4*)(Wz + (size_t)(r0 + tr) * N + c0 + tc);
    tile[tr][tc + 0] = v.x; tile[tr][tc + 1] = v.y;
    tile[tr][tc + 2] = v.z; tile[tr][tc + 3] = v.w;
    __syncthreads();
    f16x4 h4, l4;
#pragma unroll
    for (int q = 0; q < 4; ++q) {
        const float f = tile[tc + q][tr];     // W[r0+tc+q][c0+tr]
        const f16 h = (f16)f;
        h4[q] = h; l4[q] = (f16)(f - (float)h);
    }
    // n = c0+tr, k = r0+tc..+3 ; ks = r0>>5 (tc<32), within-32 = tc..tc+3
    const size_t oidx = zoff + (size_t)(r0 >> 5) * N * 32 + (size_t)(c0 + tr) * 32 + tc;
    *(f16x4*)(ohi + oidx) = h4;
    *(f16x4*)(olo + oidx) = l4;
}

// ---------------- split-fp16 MFMA grouped GEMM (2-phase, coalesced) --------
// C(128x128) = A(128x1024) @ B(1024x128), 3-term hi/lo split, fp32 accum.
// All operands K-blocked [ks][row][32]; staging loads are contiguous 1KB per
// issue with a chunk-XOR (c ^ (row>>1)&3) folded into the SOURCE address;
// frag reads apply the same XOR.
// 1-D grid, XCD-chunked bijective remap (nwg % 8 == 0 by construction),
// n-tile fastest in LOGICAL order -> each XCD owns complete slot-panels.
// mode 0: FFN GEMM1  - A gathered from xK planes via rowlist; gelu; HK out
// mode 1: FFN GEMM2  - A = HK planes (chunk-local); gate * y atomicAdd outF
// mode 2: head GEMM  - A = xK planes (row = slot); gelu; fp32 out (ld Ncols)
__global__ __launch_bounds__(256) void mfma_gemm_kernel(
    const f16* __restrict__ Ahi, const f16* __restrict__ Alo,
    const int* __restrict__ rowlist, const int* __restrict__ offp,
    const f16* __restrict__ Whi, const f16* __restrict__ Wlo,
    const float* __restrict__ biasbase, const float* __restrict__ slotgate,
    f16* __restrict__ Hhi, f16* __restrict__ Hlo,
    float* __restrict__ outF,
    int mode, int s0, int Ncols, int plainM, int ArowsA, int HrowsOut)
{
    // ---- XCD-chunked bijective remap: XCD (bid%8) gets contiguous logical
    // chunk; logical order is n-tile-fast so one XCD sees all 8 n-tiles of
    // each slot-panel consecutively (A-panel L2 reuse).
    const int nwg = gridDim.x;
    const int qch = nwg >> 3;                 // nwg % 8 == 0 by construction
    const int wgid = (blockIdx.x & 7) * qch + (blockIdx.x >> 3);
    const int nN = Ncols >> 7;
    const int n0 = (wgid % nN) << 7;
    const int slot0 = s0 + (wgid / nN) * 128;

    int t = 0;
    if (mode != 2) {
        if (slot0 >= offp[T]) return;
        while (t < T - 1 && offp[t + 1] <= slot0) ++t;   // bounded search
    } else {
        if (slot0 >= plainM) return;
    }
    const int tid = threadIdx.x;
    const int wave = tid >> 6, lane = tid & 63;

    // LDS: 2 buffers x [plane 0=Ahi 1=Alo 2=Bhi 3=Blo][row 128][32 halves]
    __shared__ f16 lds[2][4][128][32];       // 64 KB

    // 32 coalesced 1KB issues per K-step; wave w takes iss = w + 4*s.
    // Issue (plane b, sub j): LDS halves j*512 + lane*8; global source is the
    // 64B row-chunk of row (j*16 + lane>>2), chunk (lane&3) ^ ((row>>1)&3).
    const int rsub = lane >> 2, csub = lane & 3;
    const f16* gp[8];
    f16* lp[8];
    size_t str[8];
#pragma unroll
    for (int s = 0; s < 8; ++s) {
        const int iss = wave + 4 * s;
        const int b = iss >> 3, j = iss & 7;
        const int r = j * 16 + rsub;                 // LDS row 0..127
        const int cs = csub ^ ((r >> 1) & 3);        // source k-quad
        lp[s] = &lds[0][b][0][0] + (size_t)j * 512 + (size_t)lane * 8;
        if (b < 2) {
            const f16* plane = b ? Alo : Ahi;
            int row;
            if (mode == 0) {
                const int g = rowlist[slot0 + r];
                row = (g < 0 || g >= ArowsA) ? 0 : g;    // defensive clamp
            }
            else if (mode == 1) row = slot0 - s0 + r;
            else row = slot0 + r;
            gp[s] = plane + (size_t)row * 32 + (size_t)cs * 8;
            str[s] = (size_t)ArowsA * 32;
        } else {
            const f16* plane = (b == 3) ? Wlo : Whi;
            gp[s] = plane + (size_t)t * D * Ncols + (size_t)(n0 + r) * 32 + (size_t)cs * 8;
            str[s] = (size_t)Ncols * 32;
        }
    }

    f32x4 acc[4][4];
#pragma unroll
    for (int i = 0; i < 4; ++i)
#pragma unroll
        for (int j = 0; j < 4; ++j) acc[i][j] = (f32x4){0.f, 0.f, 0.f, 0.f};

    const int wr = wave >> 1, wc = wave & 1;
    const int qd = lane >> 4, m16 = lane & 15;
    const int swzh = (qd ^ ((m16 >> 1) & 3)) * 8;    // frag-read chunk XOR

    // ---- prologue: stage K-step 0 into buffer 0, drain, sync ----
#pragma unroll
    for (int s = 0; s < 8; ++s) { async16(gp[s], lp[s]); gp[s] += str[s]; }
    asm volatile("s_waitcnt vmcnt(0)" ::: "memory");
    __builtin_amdgcn_s_barrier();
    asm volatile("" ::: "memory");

    // ---- main loop: 31 pipelined steps (stage t+1 || compute t) ----
#pragma unroll 2
    for (int kt = 0; kt < 31; ++kt) {
        const int cur = kt & 1, nxt = cur ^ 1;
#pragma unroll
        for (int s = 0; s < 8; ++s) { async16(gp[s], lp[s] + (size_t)nxt * 16384); gp[s] += str[s]; }

        f16x8 ah[4], al[4], bh[4], bl[4];
#pragma unroll
        for (int i = 0; i < 4; ++i) {
            ah[i] = *(const f16x8*)&lds[cur][0][wr * 64 + i * 16 + m16][swzh];
            al[i] = *(const f16x8*)&lds[cur][1][wr * 64 + i * 16 + m16][swzh];
            bh[i] = *(const f16x8*)&lds[cur][2][wc * 64 + i * 16 + m16][swzh];
            bl[i] = *(const f16x8*)&lds[cur][3][wc * 64 + i * 16 + m16][swzh];
        }
        __builtin_amdgcn_s_setprio(1);
#pragma unroll
        for (int i = 0; i < 4; ++i)
#pragma unroll
            for (int j = 0; j < 4; ++j) {
                acc[i][j] = __builtin_amdgcn_mfma_f32_16x16x32_f16(ah[i], bh[j], acc[i][j], 0, 0, 0);
                acc[i][j] = __builtin_amdgcn_mfma_f32_16x16x32_f16(al[i], bh[j], acc[i][j], 0, 0, 0);
                acc[i][j] = __builtin_amdgcn_mfma_f32_16x16x32_f16(ah[i], bl[j], acc[i][j], 0, 0, 0);
            }
        __builtin_amdgcn_s_setprio(0);
        asm volatile("s_waitcnt vmcnt(0)" ::: "memory");
        __builtin_amdgcn_s_barrier();
        asm volatile("" ::: "memory");
    }

    // ---- epilogue compute: K-step 31 lives in buffer 1 ----
    {
        f16x8 ah[4], al[4], bh[4], bl[4];
#pragma unroll
        for (int i = 0; i < 4; ++i) {
            ah[i] = *(const f16x8*)&lds[1][0][wr * 64 + i * 16 + m16][swzh];
            al[i] = *(const f16x8*)&lds[1][1][wr * 64 + i * 16 + m16][swzh];
            bh[i] = *(const f16x8*)&lds[1][2][wc * 64 + i * 16 + m16][swzh];
            bl[i] = *(const f16x8*)&lds[1][3][wc * 64 + i * 16 + m16][swzh];
        }
        __builtin_amdgcn_s_setprio(1);
#pragma unroll
        for (int i = 0; i < 4; ++i)
#pragma unroll
            for (int j = 0; j < 4; ++j) {
                acc[i][j] = __builtin_amdgcn_mfma_f32_16x16x32_f16(ah[i], bh[j], acc[i][j], 0, 0, 0);
                acc[i][j] = __builtin_amdgcn_mfma_f32_16x16x32_f16(al[i], bh[j], acc[i][j], 0, 0, 0);
                acc[i][j] = __builtin_amdgcn_mfma_f32_16x16x32_f16(ah[i], bl[j], acc[i][j], 0, 0, 0);
            }
        __builtin_amdgcn_s_setprio(0);
    }

    float bj[4];
#pragma unroll
    for (int j = 0; j < 4; ++j)
        bj[j] = biasbase[(size_t)t * Ncols + n0 + wc * 64 + j * 16 + m16];

    if (mode == 0) {
        // write H in K-blocked layout [ks][ls][32] (consumed by GEMM2 staging)
#pragma unroll
        for (int i = 0; i < 4; ++i)
#pragma unroll
            for (int r = 0; r < 4; ++r) {
                const int lsg = slot0 - s0 + wr * 64 + i * 16 + qd * 4 + r;
#pragma unroll
                for (int j = 0; j < 4; ++j) {
                    const float v = gelu_f(acc[i][j][r] + bj[j]);
                    const f16 h = (f16)v;
                    const int col = n0 + wc * 64 + j * 16 + m16;
                    const size_t off = (size_t)(col >> 5) * ((size_t)HrowsOut * 32)
                                     + (size_t)lsg * 32 + (col & 31);
                    Hhi[off] = h;
                    Hlo[off] = (f16)(v - (float)h);
                }
            }
    } else if (mode == 1) {
#pragma unroll
        for (int i = 0; i < 4; ++i)
#pragma unroll
            for (int r = 0; r < 4; ++r) {
                const int s_ = slot0 + wr * 64 + i * 16 + qd * 4 + r;
                const int grow = rowlist[s_];
                if (grow < 0) continue;
                const float g = slotgate[s_];
                float* op = outF + (size_t)grow * 1024 + n0 + wc * 64 + m16;
#pragma unroll
                for (int j = 0; j < 4; ++j)
                    atomicAdd(op + j * 16, g * (acc[i][j][r] + bj[j]));
            }
    } else {
#pragma unroll
        for (int i = 0; i < 4; ++i)
#pragma unroll
            for (int r = 0; r < 4; ++r) {
                const int row = slot0 + wr * 64 + i * 16 + qd * 4 + r;
                float* op = outF + (size_t)row * Ncols + n0 + wc * 64 + m16;
#pragma unroll
                for (int j = 0; j < 4; ++j)
                    op[j * 16] = gelu_f(acc[i][j][r] + bj[j]);
            }
    }
}

// ---------------- residual + LN (+split x, K-blocked) ----------------------
__global__ __launch_bounds__(256) void ln_kernel(
    float* __restrict__ x, const float* __restrict__ res,
    const float* __restrict__ g, const float* __restrict__ b,
    f16* __restrict__ xhi, f16* __restrict__ xlo, int Bn)
{
    const int row = blockIdx.x, tid = threadIdx.x;
    const int d = tid << 2;
    float4 v = *(float4*)(x + (size_t)row * D + d);
    const float4 r = *(const float4*)(res + (size_t)row * D + d);
    v.x += r.x; v.y += r.y; v.z += r.z; v.w += r.w;
    __shared__ float red[256];
    red[tid] = v.x + v.y + v.z + v.w;
    __syncthreads();
    for (int st = 128; st > 0; st >>= 1) { if (tid < st) red[tid] += red[tid + st]; __syncthreads(); }
    const float mean = red[0] * (1.0f / 1024.0f);
    __syncthreads();
    const float dx0 = v.x - mean, dx1 = v.y - mean, dx2 = v.z - mean, dx3 = v.w - mean;
    red[tid] = dx0 * dx0 + dx1 * dx1 + dx2 * dx2 + dx3 * dx3;
    __syncthreads();
    for (int st = 128; st > 0; st >>= 1) { if (tid < st) red[tid] += red[tid + st]; __syncthreads(); }
    const float rstd = rsqrtf(red[0] * (1.0f / 1024.0f) + 1e-5f);
    const float4 g4 = *(const float4*)(g + d);
    const float4 b4 = *(const float4*)(b + d);
    float4 o;
    o.x = dx0 * rstd * g4.x + b4.x;
    o.y = dx1 * rstd * g4.y + b4.y;
    o.z = dx2 * rstd * g4.z + b4.z;
    o.w = dx3 * rstd * g4.w + b4.w;
    *(float4*)(x + (size_t)row * D + d) = o;
    f16x4 hv, lv;
    hv[0] = (f16)o.x; lv[0] = (f16)(o.x - (float)hv[0]);
    hv[1] = (f16)o.y; lv[1] = (f16)(o.y - (float)hv[1]);
    hv[2] = (f16)o.z; lv[2] = (f16)(o.z - (float)hv[2]);
    hv[3] = (f16)o.w; lv[3] = (f16)(o.w - (float)hv[3]);
    const size_t xko = ((size_t)(tid >> 3) * Bn + row) * 32 + (tid & 7) * 4;
    *(f16x4*)(xhi + xko) = hv;
    *(f16x4*)(xlo + xko) = lv;
}

// ---------------- final small head ----------------------------------------
__global__ __launch_bounds__(64) void head_final_kernel(
    const float* __restrict__ Hs, const float* __restrict__ Hd,
    const float* __restrict__ Ws2, const float* __restrict__ bs2,
    const float* __restrict__ Wd2, const float* __restrict__ bd2,
    float* __restrict__ outp)
{
    const int row = blockIdx.x, lane = threadIdx.x;
    float acc[11] = {};
    for (int m = 0; m < 8; ++m) {
        const int k = lane + 64 * m;
        const float hs = Hs[(size_t)row * 512 + k];
#pragma unroll
        for (int j = 0; j < 5; ++j) acc[j] += hs * Ws2[k * 5 + j];
        const float hd = Hd[(size_t)row * 512 + k];
#pragma unroll
        for (int j = 0; j < 6; ++j) acc[5 + j] += hd * Wd2[k * 6 + j];
    }
#pragma unroll
    for (int off = 32; off > 0; off >>= 1)
#pragma unroll
        for (int j = 0; j < 11; ++j) acc[j] += __shfl_down(acc[j], off);
    if (lane == 0) {
        for (int j = 0; j < 5; ++j) outp[(size_t)row * 11 + j] = acc[j] + bs2[j];
        for (int j = 0; j < 6; ++j) outp[(size_t)row * 11 + 5 + j] = acc[5 + j] + bd2[j];
    }
}

// ---------------------------------------------------------------------------
extern "C" void kernel_launch(void* const* d_in, const int* in_sizes, int n_in,
                              void* d_out, int out_size, void* d_ws, size_t ws_size,
                              hipStream_t stream)
{
    const int*   a    = (const int*)d_in[0];
    const int*   bI   = (const int*)d_in[1];
    const float* Win  = (const float*)d_in[2];
    const float* bin_ = (const float*)d_in[3];
    const float* g_in = (const float*)d_in[4];
    const float* b_ln = (const float*)d_in[5];
    const float* Wr   = (const float*)d_in[6];
    const float* W1   = (const float*)d_in[7];
    const float* b1   = (const float*)d_in[8];
    const float* W2   = (const float*)d_in[9];
    const float* b2   = (const float*)d_in[10];
    const float* g_l  = (const float*)d_in[11];
    const float* b_l  = (const float*)d_in[12];
    const float* Ws1  = (const float*)d_in[13];
    const float* bs1  = (const float*)d_in[14];
    const float* Ws2  = (const float*)d_in[15];
    const float* bs2  = (const float*)d_in[16];
    const float* Wd1  = (const float*)d_in[17];
    const float* bd1  = (const float*)d_in[18];
    const float* Wd2  = (const float*)d_in[19];
    const float* bd2  = (const float*)d_in[20];
    const int Bn = in_sizes[0];                 // 16384
    float* outF = (float*)d_out;

    const long maxslots = (long)Bn * KSEL + (long)T * PAD;  // 67584

    // ---- workspace carve (256 B aligned) ----
    char* p = (char*)d_ws;
    auto alloc = [&](size_t bytes) -> char* {
        char* r = p;
        p += (bytes + 255) & ~(size_t)255;
        return r;
    };
    float* x      = (float*)alloc((size_t)Bn * D * 4);
    f16*   xhi    = (f16*)alloc((size_t)Bn * D * 2);
    f16*   xlo    = (f16*)alloc((size_t)Bn * D * 2);
    float* outacc = (float*)alloc((size_t)Bn * D * 4);
    f16* WtAh = (f16*)alloc((size_t)T * D * D * 2);
    f16* WtAl = (f16*)alloc((size_t)T * D * D * 2);
    f16* WtBh = (f16*)alloc((size_t)T * D * D * 2);
    f16* WtBl = (f16*)alloc((size_t)T * D * D * 2);
    f16* Wtsh = (f16*)alloc((size_t)D * 512 * 2);
    f16* Wtsl = (f16*)alloc((size_t)D * 512 * 2);
    f16* Wtdh = (f16*)alloc((size_t)D * 512 * 2);
    f16* Wtdl = (f16*)alloc((size_t)D * 512 * 2);
    float* gates    = (float*)alloc((size_t)Bn * KSEL * 4);
    float* slotgate = (float*)alloc((size_t)maxslots * 4);
    int*   topi     = (int*)alloc((size_t)Bn * KSEL * 4);
    int*   rowlist  = (int*)alloc((size_t)maxslots * 4);
    int*   counts   = (int*)alloc(T * 4);
    int*   offp     = (int*)alloc((T + 1) * 4);
    int*   cur      = (int*)alloc(T * 4);
    const size_t used = (size_t)(p - (char*)d_ws);
    const size_t avail = (ws_size > used) ? (ws_size - used) : 0;

    // H chunk: Hhi+Hlo = 4096 B per slot. Heads later overlay fp32 Hs/Hd here.
    long hcap = (long)(avail / 4096);
    hcap &= ~(long)(PAD - 1);
    if (hcap > maxslots) hcap = maxslots;
    if (hcap < Bn) hcap = Bn;    // floor so head buffers (Bn*512*2 fp32) fit
    f16* Hhi = (f16*)p;
    f16* Hlo = Hhi + (size_t)hcap * D;
    float* Hs = (float*)p;
    float* Hd = Hs + (size_t)Bn * 512;
    const int nchunks = (int)((maxslots + hcap - 1) / hcap);
    const int mblocks = (int)(hcap / PAD);

    // ---- launches ----
    encode_kernel<<<Bn, 256, 0, stream>>>(a, bI, Win, bin_, g_in, b_ln, x, xhi, xlo, Bn);
    tspl_kernel<<<dim3(32, 16, 1), 256, 0, stream>>>(Ws1, Wtsh, Wtsl, D, 512);
    tspl_kernel<<<dim3(32, 16, 1), 256, 0, stream>>>(Wd1, Wtdh, Wtdl, D, 512);

    const long initn = (long)Bn * D;
    const int initblocks = (int)((initn + 255) / 256);
    for (int i = 0; i < 3; ++i) {
        init_layer_kernel<<<initblocks, 256, 0, stream>>>(outacc, rowlist, counts,
                                                          initn, (int)maxslots);
        router_kernel<<<(Bn + 127) / 128, 256, 0, stream>>>(x, Wr, i, gates, topi,
                                                            counts, Bn);
        scan_kernel<<<1, 64, 0, stream>>>(counts, offp, cur);
        scatter_kernel<<<(Bn + 255) / 256, 256, 0, stream>>>(topi, gates, offp, cur,
                                                             rowlist, slotgate, Bn);
        tspl_kernel<<<dim3(32, 32, 16), 256, 0, stream>>>(W1 + (size_t)i * T * D * D,
                                                          WtAh, WtAl, D, D);
        tspl_kernel<<<dim3(32, 32, 16), 256, 0, stream>>>(W2 + (size_t)i * T * D * D,
                                                          WtBh, WtBl, D, D);
        const float* b1i = b1 + (size_t)i * T * D;
        const float* b2i = b2 + (size_t)i * T * D;
        for (int c = 0; c < nchunks; ++c) {
            const int s0 = (int)((long)c * hcap);
            const int nwgF = (D / 128) * mblocks;   // % 8 == 0 (mblocks mult of 8? 528*8 ok; general: D/128=8)
            mfma_gemm_kernel<<<nwgF, 256, 0, stream>>>(
                xhi, xlo, rowlist, offp, WtAh, WtAl, b1i, nullptr,
                Hhi, Hlo, nullptr, 0, s0, D, 0, Bn, (int)hcap);
            mfma_gemm_kernel<<<nwgF, 256, 0, stream>>>(
                Hhi, Hlo, rowlist, offp, WtBh, WtBl, b2i, slotgate,
                nullptr, nullptr, outacc, 1, s0, D, 0, (int)hcap, (int)hcap);
        }
        ln_kernel<<<Bn, 256, 0, stream>>>(x, outacc, g_l + (size_t)i * D,
                                          b_l + (size_t)i * D, xhi, xlo, Bn);
    }

    // heads: Hs = gelu(x@Ws1+bs1), Hd = gelu(x@Wd1+bd1) via MFMA, then tiny head
    const int nwgH = (512 / 128) * (Bn / 128);   // 4 * 128 = 512, % 8 == 0
    mfma_gemm_kernel<<<nwgH, 256, 0, stream>>>(
        xhi, xlo, nullptr, nullptr, Wtsh, Wtsl, bs1, nullptr,
        nullptr, nullptr, Hs, 2, 0, 512, Bn, Bn, 0);
    mfma_gemm_kernel<<<nwgH, 256, 0, stream>>>(
        xhi, xlo, nullptr, nullptr, Wtdh, Wtdl, bd1, nullptr,
        nullptr, nullptr, Hd, 2, 0, 512, Bn, Bn, 0);
    head_final_kernel<<<Bn, 64, 0, stream>>>(Hs, Hd, Ws2, bs2, Wd2, bd2, outF);
}